// Round 1
// baseline (476.444 us; speedup 1.0000x reference)
//
#include <hip/hip_runtime.h>
#include <hip/hip_bf16.h>

typedef __hip_bfloat16 bf16;
typedef __attribute__((ext_vector_type(8))) short short8;
typedef __attribute__((ext_vector_type(4))) float float4v;

#define NN 20000
#define EE 160000
#define ET (NN + EE)

__device__ __forceinline__ float bf2f(bf16 v){ return __bfloat162float(v); }
__device__ __forceinline__ float raw2f(unsigned short u){ return __uint_as_float(((unsigned)u) << 16); }
__device__ __forceinline__ unsigned short f2raw(float f){
  bf16 h = __float2bfloat16(f);
  return *(unsigned short*)&h;
}

// ---------------- inline dtype detection (per-wave ballot; all waves agree) ----------------
__device__ __forceinline__ int detect_f32(const void* raw, int nwords, int lane){
  unsigned v = ((const unsigned*)raw)[lane % nwords];
  int e8 = (v >> 7) & 0xFF;
  int looks = (e8 >= 100 && e8 <= 140) ? 1 : 0;
  unsigned long long mz = __ballot(v == 0u);
  unsigned long long ml = __ballot(looks);
  int nz = __popcll(mz);
  int nonz = 64 - nz;
  int nl = __popcll(ml);
  return (nonz > 0 && 2*nl >= nonz) ? 0 : 1;
}

__device__ __forceinline__ int detect_i64(const int* eiraw, int lane){
  int odd = eiraw[2*lane + 1];
  unsigned long long m2 = __ballot(odd != 0);
  return (m2 == 0ULL) ? 1 : 0;
}

// ---------------- fused preprocessing kernel ----------------
struct P13 { const void* src[13]; int off[13]; int n[13]; };
struct PrepArgs {
  const void* xraw; bf16* Xc;
  const void* w1raw; bf16* Wt1;
  const void* w2raw; bf16* Wt2;
  const void* w3raw; bf16* Wt3;
  const int* eiraw; int* eic;
  P13 p13; float* prm;
  int* counts;
  float* esA; float* edA;
};

__device__ __forceinline__ void do_transpose(float (*tile)[33], const void* raw,
    bf16* wt, int K, int M, int f, int bx, int by, int t){
  int kb = by*32, mb = bx*32;
  int tx = t & 31, ty = t >> 5;   // 32 x 8
  for (int r = 0; r < 4; r++){
    int k = kb + ty + r*8;
    int m = mb + tx;
    float v = f ? ((const float*)raw)[(size_t)k*M+m] : bf2f(((const bf16*)raw)[(size_t)k*M+m]);
    tile[ty + r*8][tx] = v;
  }
  __syncthreads();
  for (int r = 0; r < 4; r++){
    int m = mb + ty + r*8;
    int k = kb + tx;
    wt[(size_t)m*K + k] = __float2bfloat16(tile[tx][ty + r*8]);
  }
}

__global__ __launch_bounds__(256) void k_prep(PrepArgs A){
  __shared__ float tile[32][33];
  int b = blockIdx.x, t = threadIdx.x;
  int lane = t & 63;
  if (b < 10000){                                 // cvt X -> bf16
    int f = detect_f32(A.xraw, NN*128/2, lane);
    int i = b*256 + t;
    if (f) A.Xc[i] = __float2bfloat16(((const float*)A.xraw)[i]);
    else   A.Xc[i] = ((const bf16*)A.xraw)[i];
  } else if (b < 10128){                          // transpose W1 [128][1024] -> [1024][128]
    int f = detect_f32(A.w1raw, 128*1024/2, lane);
    int r = b - 10000;
    do_transpose(tile, A.w1raw, A.Wt1, 128, 1024, f, r & 31, r >> 5, t);
  } else if (b < 11152){                          // transpose W2 [1024][1024]
    int f = detect_f32(A.w2raw, 1024*1024/2, lane);
    int r = b - 10128;
    do_transpose(tile, A.w2raw, A.Wt2, 1024, 1024, f, r & 31, r >> 5, t);
  } else if (b < 11664){                          // transpose W3 [1024][512] -> [512][1024]
    int f = detect_f32(A.w3raw, 1024*512/2, lane);
    int r = b - 11152;
    do_transpose(tile, A.w3raw, A.Wt3, 1024, 512, f, r & 15, r >> 4, t);
  } else if (b < 12914){                          // cvte
    int f64 = detect_i64(A.eiraw, lane);
    int i = (b - 11664)*256 + t;
    if (i < 2*EE) A.eic[i] = f64 ? A.eiraw[2*i] : A.eiraw[i];
  } else if (b < 12927){                          // params -> fp32
    int pb = b - 12914;
    const void* s = A.p13.src[pb];
    int n = A.p13.n[pb];
    int f = detect_f32(s, n/2, lane);
    float* d = A.prm + A.p13.off[pb];
    for (int i = t; i < n; i += 256)
      d[i] = f ? ((const float*)s)[i] : bf2f(((const bf16*)s)[i]);
  } else if (b < 13006){                          // init_counts
    int i = (b - 12927)*256 + t;
    if (i < NN) A.counts[i] = 1;
  } else {                                        // zero esA/edA (NN*4 floats each)
    int i = (b - 13006)*256 + t;
    if (i < NN*4){ A.esA[i] = 0.f; A.edA[i] = 0.f; }
  }
}

// ---------------- CSR build ----------------
__global__ void k_hist(const int* __restrict__ ei, int* __restrict__ counts){
  int e = blockIdx.x*256 + threadIdx.x;
  if (e < EE){
    int d = ei[EE + e];
    if (d >= 0 && d < NN) atomicAdd(&counts[d], 1);
  }
}

// scan + self-loop insertion fused; counts/rp/cursor/col are DISTINCT buffers (no aliasing)
__global__ __launch_bounds__(1024) void k_scan(const int* __restrict__ counts, int* __restrict__ rp,
    int* __restrict__ cursor, int* __restrict__ col){
  __shared__ int wsum[16];
  __shared__ int sc;
  int t = threadIdx.x, lane = t & 63, wv = t >> 6;
  if (t == 0) sc = 0;
  __syncthreads();
  for (int base = 0; base < NN; base += 1024){
    int i = base + t;
    int v = (i < NN) ? counts[i] : 0;
    int x = v;
    #pragma unroll
    for (int o = 1; o < 64; o <<= 1){
      int y = __shfl_up(x, o, 64);
      if (lane >= o) x += y;
    }
    if (lane == 63) wsum[wv] = x;
    __syncthreads();
    if (wv == 0 && lane < 16){
      int w = wsum[lane];
      #pragma unroll
      for (int o = 1; o < 16; o <<= 1){
        int y = __shfl_up(w, o, 16);
        if ((lane & 15) >= o) w += y;
      }
      wsum[lane] = w;
    }
    __syncthreads();
    int carry = sc;
    int wpre = (wv > 0) ? wsum[wv-1] : 0;
    if (i < NN){
      int p = carry + wpre + x - v;   // exclusive
      rp[i] = p;
      col[p] = i;                     // self loop at segment head
      cursor[i] = p + 1;
    }
    __syncthreads();
    if (t == 1023) sc = carry + wsum[15];
    __syncthreads();
  }
  if (t == 0) rp[NN] = sc;
}

__global__ void k_scatter(const int* __restrict__ ei, int* __restrict__ cursor, int* __restrict__ col){
  int e = blockIdx.x*256 + threadIdx.x;
  if (e < EE){
    int s = ei[e], d = ei[EE + e];
    if (d >= 0 && d < NN){
      int pos = atomicAdd(&cursor[d], 1);
      col[pos] = s;
    }
  }
}

// ---------------- MFMA GEMM: 128x128 tile, BK=64, XOR-swizzled LDS, fused fp32 es/ed ----------------
// m97-structure tile-space (learn_hip m92/m103/m105/m112): 64^2=343, 128^2=912, 256^2=792 TF.
// 128x128 doubles MFMA:ds_read ratio (32:16 vs 16:12 per K-step/wave) and halves B-panel refetch.
// Grid 157x8 = 1256 blocks = exactly ~5 rounds of 256 CUs (near-perfect balance; 8-phase 256^2
// template would quantize to 316/158 blocks -> no win at these shapes).
// Per-element K-accumulation order identical to the 64x128 version (bit-identical output).
__global__ __launch_bounds__(256) void k_gemm_mfma(
    const bf16* __restrict__ X, const bf16* __restrict__ Wt, bf16* __restrict__ Y,
    const float* __restrict__ as_, const float* __restrict__ ad_,
    float* __restrict__ es, float* __restrict__ ed,
    int K, int M, int C, int H)
{
  __shared__ bf16 Xs[128*64];   // 16 KB
  __shared__ bf16 Bs[128*64];   // 16 KB
  int ncols = gridDim.x;
  int bid = blockIdx.y * ncols + blockIdx.x;
  int xcd  = bid & 7;
  int rest = bid >> 3;
  int colb = rest % ncols;
  int rowb = xcd + 8 * (rest / ncols);
  int r0 = rowb * 128;
  if (r0 >= NN) return;
  int c0 = colb * 128;

  int tid  = threadIdx.x;
  int wave = tid >> 6, lane = tid & 63;
  int quad = lane >> 4, l15 = lane & 15;
  int wr = (wave >> 1) * 64;     // 2 row-groups of 64
  int wc = (wave & 1) * 64;      // 2 col-groups of 64
  int sw = l15 & 7;

  float4v acc[4][4];
  #pragma unroll
  for (int i=0;i<4;i++)
    #pragma unroll
    for (int j=0;j<4;j++)
      acc[i][j] = (float4v){0.f,0.f,0.f,0.f};

  for (int k0 = 0; k0 < K; k0 += 64){
    #pragma unroll
    for (int i = 0; i < 4; i++){            // Xs: 1024 chunks of 16B
      int ch = i*256 + tid;
      int row = ch >> 3, kl = ch & 7;
      int kg = kl ^ (row & 7);
      const bf16* gx = X + (size_t)(r0 + row)*K + k0 + kg*8;
      __builtin_amdgcn_global_load_lds(
        (const __attribute__((address_space(1))) unsigned int*)gx,
        (__attribute__((address_space(3))) unsigned int*)(Xs + ch*8), 16, 0, 0);
    }
    #pragma unroll
    for (int i = 0; i < 4; i++){            // Bs: 1024 chunks of 16B
      int ch = i*256 + tid;
      int row = ch >> 3, kl = ch & 7;
      int kg = kl ^ (row & 7);
      const bf16* gb = Wt + (size_t)(c0 + row)*K + k0 + kg*8;
      __builtin_amdgcn_global_load_lds(
        (const __attribute__((address_space(1))) unsigned int*)gb,
        (__attribute__((address_space(3))) unsigned int*)(Bs + ch*8), 16, 0, 0);
    }
    __syncthreads();

    #pragma unroll
    for (int kk = 0; kk < 2; kk++){         // two 32-wide K slices, in order (bit-identical accum)
      int kp = quad + kk*4;
      short8 af[4], bfr[4];
      #pragma unroll
      for (int i = 0; i < 4; i++){
        int r = wr + i*16 + l15;
        af[i] = *(const short8*)(Xs + ((size_t)r*8 + (kp ^ sw))*8);
      }
      #pragma unroll
      for (int j = 0; j < 4; j++){
        int r = wc + j*16 + l15;
        bfr[j] = *(const short8*)(Bs + ((size_t)r*8 + (kp ^ sw))*8);
      }
      #pragma unroll
      for (int i = 0; i < 4; i++)
        #pragma unroll
        for (int j = 0; j < 4; j++)
          acc[i][j] = __builtin_amdgcn_mfma_f32_16x16x32_bf16(af[i], bfr[j], acc[i][j], 0, 0, 0);
    }
    __syncthreads();
  }

  int h = c0 / C;
  float asv[4], adv[4];
  #pragma unroll
  for (int j = 0; j < 4; j++){
    int colj = c0 + wc + j*16 + l15;
    asv[j] = as_[colj]; adv[j] = ad_[colj];
  }
  #pragma unroll
  for (int i = 0; i < 4; i++){
    int rbase = r0 + wr + i*16 + quad*4;
    #pragma unroll
    for (int rg = 0; rg < 4; rg++){
      int row = rbase + rg;
      bool ok = (row < NN);
      float pe = 0.f, pd = 0.f;
      #pragma unroll
      for (int j = 0; j < 4; j++){
        float v = acc[i][j][rg];
        int colj = c0 + wc + j*16 + l15;
        if (ok) Y[(size_t)row*M + colj] = __float2bfloat16(v);
        pe += v * asv[j];
        pd += v * adv[j];
      }
      #pragma unroll
      for (int o = 1; o < 16; o <<= 1){
        pe += __shfl_xor(pe, o, 64);
        pd += __shfl_xor(pd, o, 64);
      }
      if (ok && l15 == 0){
        atomicAdd(&es[row*H + h], pe);
        atomicAdd(&ed[row*H + h], pd);
      }
    }
  }
}

// ---------------- wave-per-node softmax+aggregate+bias+LN+ELU (layers 1,2; H=4) ----------------
__global__ __launch_bounds__(256) void k_aggln(const int* __restrict__ rp, const int* __restrict__ col,
    const bf16* __restrict__ xw, const float* __restrict__ es, const float* __restrict__ ed,
    const float* __restrict__ bias, const float* __restrict__ gam, const float* __restrict__ bet,
    bf16* __restrict__ act, float* __restrict__ esz, float* __restrict__ edz, int zn){
  int wv = threadIdx.x >> 6, lane = threadIdx.x & 63;
  int n = blockIdx.x*4 + wv;              // NN % 4 == 0
  int h = lane >> 4;
  int cb = lane * 16;
  int e0 = rp[n], e1 = rp[n+1], deg = e1 - e0;
  float4 ed4 = *(const float4*)&ed[n*4];
  const unsigned short* xwu = (const unsigned short*)xw;

  float acc[16];
  #pragma unroll
  for (int c=0;c<16;c++) acc[c]=0.f;

  if (deg <= 64){
    int src = 0;
    float l0=-1e30f, l1=-1e30f, l2=-1e30f, l3=-1e30f;
    if (lane < deg){
      src = col[e0 + lane];
      float4 e4 = *(const float4*)&es[src*4];
      float v;
      v = e4.x + ed4.x; l0 = v > 0.f ? v : 0.2f*v;
      v = e4.y + ed4.y; l1 = v > 0.f ? v : 0.2f*v;
      v = e4.z + ed4.z; l2 = v > 0.f ? v : 0.2f*v;
      v = e4.w + ed4.w; l3 = v > 0.f ? v : 0.2f*v;
    }
    float m0=l0, m1=l1, m2=l2, m3=l3;
    #pragma unroll
    for (int o=1;o<64;o<<=1){
      m0 = fmaxf(m0, __shfl_xor(m0,o,64));
      m1 = fmaxf(m1, __shfl_xor(m1,o,64));
      m2 = fmaxf(m2, __shfl_xor(m2,o,64));
      m3 = fmaxf(m3, __shfl_xor(m3,o,64));
    }
    float p0 = (lane<deg) ? __expf(l0-m0) : 0.f;
    float p1 = (lane<deg) ? __expf(l1-m1) : 0.f;
    float p2 = (lane<deg) ? __expf(l2-m2) : 0.f;
    float p3 = (lane<deg) ? __expf(l3-m3) : 0.f;
    float d0=p0, d1=p1, d2=p2, d3=p3;
    #pragma unroll
    for (int o=1;o<64;o<<=1){
      d0 += __shfl_xor(d0,o,64);
      d1 += __shfl_xor(d1,o,64);
      d2 += __shfl_xor(d2,o,64);
      d3 += __shfl_xor(d3,o,64);
    }
    float al0 = p0 * (1.f/(d0+1e-16f));
    float al1 = p1 * (1.f/(d1+1e-16f));
    float al2 = p2 * (1.f/(d2+1e-16f));
    float al3 = p3 * (1.f/(d3+1e-16f));

    int j = 0;
    for (; j + 2 <= deg; j += 2){
      int sA = __shfl(src, j, 64);
      int sB = __shfl(src, j+1, 64);
      float a0A = __shfl(al0, j, 64), a1A = __shfl(al1, j, 64);
      float a2A = __shfl(al2, j, 64), a3A = __shfl(al3, j, 64);
      float a0B = __shfl(al0, j+1, 64), a1B = __shfl(al1, j+1, 64);
      float a2B = __shfl(al2, j+1, 64), a3B = __shfl(al3, j+1, 64);
      float aA = (h==0) ? a0A : ((h==1) ? a1A : ((h==2) ? a2A : a3A));
      float aB = (h==0) ? a0B : ((h==1) ? a1B : ((h==2) ? a2B : a3B));
      const unsigned short* rA = xwu + (size_t)sA*1024 + cb;
      const unsigned short* rB = xwu + (size_t)sB*1024 + cb;
      ushort4 uA0 = *(const ushort4*)(rA);
      ushort4 uA1 = *(const ushort4*)(rA+4);
      ushort4 uA2 = *(const ushort4*)(rA+8);
      ushort4 uA3 = *(const ushort4*)(rA+12);
      ushort4 uB0 = *(const ushort4*)(rB);
      ushort4 uB1 = *(const ushort4*)(rB+4);
      ushort4 uB2 = *(const ushort4*)(rB+8);
      ushort4 uB3 = *(const ushort4*)(rB+12);
      acc[0] += aA*raw2f(uA0.x); acc[1] += aA*raw2f(uA0.y); acc[2] += aA*raw2f(uA0.z); acc[3] += aA*raw2f(uA0.w);
      acc[4] += aA*raw2f(uA1.x); acc[5] += aA*raw2f(uA1.y); acc[6] += aA*raw2f(uA1.z); acc[7] += aA*raw2f(uA1.w);
      acc[8] += aA*raw2f(uA2.x); acc[9] += aA*raw2f(uA2.y); acc[10]+= aA*raw2f(uA2.z); acc[11]+= aA*raw2f(uA2.w);
      acc[12]+= aA*raw2f(uA3.x); acc[13]+= aA*raw2f(uA3.y); acc[14]+= aA*raw2f(uA3.z); acc[15]+= aA*raw2f(uA3.w);
      acc[0] += aB*raw2f(uB0.x); acc[1] += aB*raw2f(uB0.y); acc[2] += aB*raw2f(uB0.z); acc[3] += aB*raw2f(uB0.w);
      acc[4] += aB*raw2f(uB1.x); acc[5] += aB*raw2f(uB1.y); acc[6] += aB*raw2f(uB1.z); acc[7] += aB*raw2f(uB1.w);
      acc[8] += aB*raw2f(uB2.x); acc[9] += aB*raw2f(uB2.y); acc[10]+= aB*raw2f(uB2.z); acc[11]+= aB*raw2f(uB2.w);
      acc[12]+= aB*raw2f(uB3.x); acc[13]+= aB*raw2f(uB3.y); acc[14]+= aB*raw2f(uB3.z); acc[15]+= aB*raw2f(uB3.w);
    }
    for (; j < deg; j++){
      int s = __shfl(src, j, 64);
      float a0j = __shfl(al0, j, 64);
      float a1j = __shfl(al1, j, 64);
      float a2j = __shfl(al2, j, 64);
      float a3j = __shfl(al3, j, 64);
      float aj = (h==0) ? a0j : ((h==1) ? a1j : ((h==2) ? a2j : a3j));
      const unsigned short* row = xwu + (size_t)s*1024 + cb;
      ushort4 u0 = *(const ushort4*)(row);
      ushort4 u1 = *(const ushort4*)(row+4);
      ushort4 u2 = *(const ushort4*)(row+8);
      ushort4 u3 = *(const ushort4*)(row+12);
      acc[0] += aj*raw2f(u0.x); acc[1] += aj*raw2f(u0.y); acc[2] += aj*raw2f(u0.z); acc[3] += aj*raw2f(u0.w);
      acc[4] += aj*raw2f(u1.x); acc[5] += aj*raw2f(u1.y); acc[6] += aj*raw2f(u1.z); acc[7] += aj*raw2f(u1.w);
      acc[8] += aj*raw2f(u2.x); acc[9] += aj*raw2f(u2.y); acc[10]+= aj*raw2f(u2.z); acc[11]+= aj*raw2f(u2.w);
      acc[12]+= aj*raw2f(u3.x); acc[13]+= aj*raw2f(u3.y); acc[14]+= aj*raw2f(u3.z); acc[15]+= aj*raw2f(u3.w);
    }
  } else {
    float edh = (h==0) ? ed4.x : ((h==1) ? ed4.y : ((h==2) ? ed4.z : ed4.w));
    float m = -1e30f;
    for (int e=e0;e<e1;e++){
      float v = es[col[e]*4 + h] + edh;
      v = v > 0.f ? v : 0.2f*v;
      m = fmaxf(m, v);
    }
    float den = 0.f;
    for (int e=e0;e<e1;e++){
      float v = es[col[e]*4 + h] + edh;
      v = v > 0.f ? v : 0.2f*v;
      den += __expf(v - m);
    }
    float rd = 1.f/(den + 1e-16f);
    for (int e=e0;e<e1;e++){
      int s = col[e];
      float v = es[s*4 + h] + edh;
      v = v > 0.f ? v : 0.2f*v;
      float aj = __expf(v - m) * rd;
      const unsigned short* row = xwu + (size_t)s*1024 + cb;
      ushort4 u0 = *(const ushort4*)(row);
      ushort4 u1 = *(const ushort4*)(row+4);
      ushort4 u2 = *(const ushort4*)(row+8);
      ushort4 u3 = *(const ushort4*)(row+12);
      acc[0] += aj*raw2f(u0.x); acc[1] += aj*raw2f(u0.y); acc[2] += aj*raw2f(u0.z); acc[3] += aj*raw2f(u0.w);
      acc[4] += aj*raw2f(u1.x); acc[5] += aj*raw2f(u1.y); acc[6] += aj*raw2f(u1.z); acc[7] += aj*raw2f(u1.w);
      acc[8] += aj*raw2f(u2.x); acc[9] += aj*raw2f(u2.y); acc[10]+= aj*raw2f(u2.z); acc[11]+= aj*raw2f(u2.w);
      acc[12]+= aj*raw2f(u3.x); acc[13]+= aj*raw2f(u3.y); acc[14]+= aj*raw2f(u3.z); acc[15]+= aj*raw2f(u3.w);
    }
  }

  #pragma unroll
  for (int c=0;c<16;c++) acc[c] += bias[cb+c];
  float s1 = 0.f, s2 = 0.f;
  #pragma unroll
  for (int c=0;c<16;c++){ s1 += acc[c]; s2 += acc[c]*acc[c]; }
  #pragma unroll
  for (int o=1;o<64;o<<=1){
    s1 += __shfl_xor(s1,o,64);
    s2 += __shfl_xor(s2,o,64);
  }
  float mu  = s1 * (1.f/1024.f);
  float var = s2 * (1.f/1024.f) - mu*mu;
  float rstd = rsqrtf(fmaxf(var, 0.f) + 1e-5f);

  ushort4 o4[4];
  #pragma unroll
  for (int q=0;q<4;q++){
    float v0 = (acc[q*4+0]-mu)*rstd*gam[cb+q*4+0] + bet[cb+q*4+0];
    float v1 = (acc[q*4+1]-mu)*rstd*gam[cb+q*4+1] + bet[cb+q*4+1];
    float v2 = (acc[q*4+2]-mu)*rstd*gam[cb+q*4+2] + bet[cb+q*4+2];
    float v3 = (acc[q*4+3]-mu)*rstd*gam[cb+q*4+3] + bet[cb+q*4+3];
    v0 = v0 > 0.f ? v0 : (__expf(v0)-1.f);
    v1 = v1 > 0.f ? v1 : (__expf(v1)-1.f);
    v2 = v2 > 0.f ? v2 : (__expf(v2)-1.f);
    v3 = v3 > 0.f ? v3 : (__expf(v3)-1.f);
    o4[q].x = f2raw(v0); o4[q].y = f2raw(v1); o4[q].z = f2raw(v2); o4[q].w = f2raw(v3);
  }
  unsigned short* dst = (unsigned short*)act + (size_t)n*1024 + cb;
  *(ushort4*)(dst)    = o4[0];
  *(ushort4*)(dst+4)  = o4[1];
  *(ushort4*)(dst+8)  = o4[2];
  *(ushort4*)(dst+12) = o4[3];

  // zero next layer's logit slots for this node (exclusive ownership; read next dispatch)
  if (lane < zn){ esz[n*zn + lane] = 0.f; edz[n*zn + lane] = 0.f; }
}

// ---------------- wave-per-node layer-3: softmax + aggregate + bias -> fp32 out (H=1) ----------------
__global__ __launch_bounds__(256) void k_agg3(const int* __restrict__ rp, const int* __restrict__ col,
    const bf16* __restrict__ xw, const float* __restrict__ es, const float* __restrict__ ed,
    const float* __restrict__ bias, float* __restrict__ out){
  int wv = threadIdx.x >> 6, lane = threadIdx.x & 63;
  int n = blockIdx.x*4 + wv;
  int cb = lane * 8;
  int e0 = rp[n], e1 = rp[n+1], deg = e1 - e0;
  float edv = ed[n];
  const unsigned short* xwu = (const unsigned short*)xw;

  float acc[8];
  #pragma unroll
  for (int c=0;c<8;c++) acc[c]=0.f;

  if (deg <= 64){
    int src = 0;
    float l = -1e30f;
    if (lane < deg){
      src = col[e0 + lane];
      float v = es[src] + edv;
      l = v > 0.f ? v : 0.2f*v;
    }
    float m = l;
    #pragma unroll
    for (int o=1;o<64;o<<=1) m = fmaxf(m, __shfl_xor(m,o,64));
    float p = (lane<deg) ? __expf(l-m) : 0.f;
    float d = p;
    #pragma unroll
    for (int o=1;o<64;o<<=1) d += __shfl_xor(d,o,64);
    float al = p * (1.f/(d+1e-16f));

    int j = 0;
    for (; j + 2 <= deg; j += 2){
      int sA = __shfl(src, j, 64);
      int sB = __shfl(src, j+1, 64);
      float aA = __shfl(al, j, 64);
      float aB = __shfl(al, j+1, 64);
      const unsigned short* rA = xwu + (size_t)sA*512 + cb;
      const unsigned short* rB = xwu + (size_t)sB*512 + cb;
      ushort4 uA0 = *(const ushort4*)(rA);
      ushort4 uA1 = *(const ushort4*)(rA+4);
      ushort4 uB0 = *(const ushort4*)(rB);
      ushort4 uB1 = *(const ushort4*)(rB+4);
      acc[0] += aA*raw2f(uA0.x); acc[1] += aA*raw2f(uA0.y); acc[2] += aA*raw2f(uA0.z); acc[3] += aA*raw2f(uA0.w);
      acc[4] += aA*raw2f(uA1.x); acc[5] += aA*raw2f(uA1.y); acc[6] += aA*raw2f(uA1.z); acc[7] += aA*raw2f(uA1.w);
      acc[0] += aB*raw2f(uB0.x); acc[1] += aB*raw2f(uB0.y); acc[2] += aB*raw2f(uB0.z); acc[3] += aB*raw2f(uB0.w);
      acc[4] += aB*raw2f(uB1.x); acc[5] += aB*raw2f(uB1.y); acc[6] += aB*raw2f(uB1.z); acc[7] += aB*raw2f(uB1.w);
    }
    for (; j < deg; j++){
      int s = __shfl(src, j, 64);
      float aj = __shfl(al, j, 64);
      const unsigned short* row = xwu + (size_t)s*512 + cb;
      ushort4 u0 = *(const ushort4*)(row);
      ushort4 u1 = *(const ushort4*)(row+4);
      acc[0] += aj*raw2f(u0.x); acc[1] += aj*raw2f(u0.y); acc[2] += aj*raw2f(u0.z); acc[3] += aj*raw2f(u0.w);
      acc[4] += aj*raw2f(u1.x); acc[5] += aj*raw2f(u1.y); acc[6] += aj*raw2f(u1.z); acc[7] += aj*raw2f(u1.w);
    }
  } else {
    float m = -1e30f;
    for (int e=e0;e<e1;e++){
      float v = es[col[e]] + edv;
      v = v > 0.f ? v : 0.2f*v;
      m = fmaxf(m, v);
    }
    float den = 0.f;
    for (int e=e0;e<e1;e++){
      float v = es[col[e]] + edv;
      v = v > 0.f ? v : 0.2f*v;
      den += __expf(v - m);
    }
    float rd = 1.f/(den + 1e-16f);
    for (int e=e0;e<e1;e++){
      int s = col[e];
      float v = es[s] + edv;
      v = v > 0.f ? v : 0.2f*v;
      float aj = __expf(v - m) * rd;
      const unsigned short* row = xwu + (size_t)s*512 + cb;
      ushort4 u0 = *(const ushort4*)(row);
      ushort4 u1 = *(const ushort4*)(row+4);
      acc[0] += aj*raw2f(u0.x); acc[1] += aj*raw2f(u0.y); acc[2] += aj*raw2f(u0.z); acc[3] += aj*raw2f(u0.w);
      acc[4] += aj*raw2f(u1.x); acc[5] += aj*raw2f(u1.y); acc[6] += aj*raw2f(u1.z); acc[7] += aj*raw2f(u1.w);
    }
  }
  float* dst = out + (size_t)n*512 + cb;
  #pragma unroll
  for (int c=0;c<8;c++) dst[c] = acc[c] + bias[cb+c];
}

__global__ void k_wssmall(float* __restrict__ out, float code){
  if (threadIdx.x == 0) out[0] = code;
}

// ---------------- launch ----------------
extern "C" void kernel_launch(void* const* d_in, const int* in_sizes, int n_in,
                              void* d_out, int out_size, void* d_ws, size_t ws_size,
                              hipStream_t stream){
  float* out = (float*)d_out;
  char* ws = (char*)d_ws;

  static const int EXP_SZ[18] = {2560000, 320000, 131072, 1024,1024,1024,1024,1024,
                                 1048576, 1024,1024,1024,1024,1024,
                                 524288, 512,512,512};
  if (n_in != 18){ k_wssmall<<<1,64,0,stream>>>(out, 500.0f*301.0f); return; }
  for (int i = 0; i < 18; i++)
    if (in_sizes[i] != EXP_SZ[i]){ k_wssmall<<<1,64,0,stream>>>(out, 500.0f*302.0f); return; }
  if (out_size != NN*512){ k_wssmall<<<1,64,0,stream>>>(out, 500.0f*303.0f); return; }
  const size_t NEED = 93215360;
  if (ws_size < NEED){ k_wssmall<<<1,64,0,stream>>>(out, 500.0f*304.0f); return; }

  // ---- workspace layout ----
  bf16* xw    = (bf16*) (ws);                    // 40,960,000 (first 80KB doubles as CSR 'counts')
  int*  cnt   = (int*)  (ws);                    // aliases xw: counts, live prep->scan
  bf16* act   = (bf16*) (ws + 40960000);         // -> 81,920,000 (first 80KB doubles as CSR 'cursor')
  int*  cursor= (int*)  (ws + 40960000);         // aliases act: live scan->scatter
  bf16* Xc    = (bf16*) (ws + 81920000);         // -> 87,040,000 (dead after gemm1)
  float* esC  = (float*)(ws + 81920000);         // aliases Xc: 80,000 B (layer-3 logits, H=1)
  float* edC  = (float*)(ws + 82000000);         // aliases Xc: 80,000 B
  bf16* Wt1   = (bf16*) (ws + 87040000);         // -> 87,302,144
  bf16* Wt2   = (bf16*) (ws + 87302144);         // -> 89,399,296
  bf16* Wt3   = (bf16*) (ws + 89399296);         // -> 90,447,872
  float* prm  = (float*)(ws + 90447872);         // -> 90,494,976
  int*  eic   = (int*)  (ws + 90495232);         // -> 91,775,232 (dead after scatter)
  float* esB  = (float*)(ws + 90495232);         // aliases eic: 320,000 B (layer-2 logits)
  float* edB  = (float*)(ws + 90815232);         // aliases eic: 320,000 B
  float* esA  = (float*)(ws + 91775232);         // -> 92,095,232 (layer-1 logits)
  float* edA  = (float*)(ws + 92095232);         // -> 92,415,232
  int*  rp    = (int*)  (ws + 92415232);         // -> 92,495,360
  int*  col   = (int*)  (ws + 92495360);         // -> 93,215,360

  float *as1=prm+0, *ad1=prm+1024, *b1=prm+2048, *lg1=prm+3072, *lb1=prm+4096;
  float *as2=prm+5120, *ad2=prm+6144, *b2=prm+7168, *lg2=prm+8192, *lb2=prm+9216;
  float *as3=prm+10240, *ad3=prm+10752, *b3=prm+11264;

  const int TB = 256;
  int gbE = (EE + TB - 1)/TB;

  // ---- fused prep ----
  {
    PrepArgs A;
    A.xraw = d_in[0]; A.Xc = Xc;
    A.w1raw = d_in[2]; A.Wt1 = Wt1;
    A.w2raw = d_in[8]; A.Wt2 = Wt2;
    A.w3raw = d_in[14]; A.Wt3 = Wt3;
    A.eiraw = (const int*)d_in[1]; A.eic = eic;
    const int idx[13] = {3,4,5,6,7, 9,10,11,12,13, 15,16,17};
    const int off[13] = {0,1024,2048,3072,4096, 5120,6144,7168,8192,9216, 10240,10752,11264};
    const int nn [13] = {1024,1024,1024,1024,1024, 1024,1024,1024,1024,1024, 512,512,512};
    for (int i=0;i<13;i++){ A.p13.src[i]=d_in[idx[i]]; A.p13.off[i]=off[i]; A.p13.n[i]=nn[i]; }
    A.prm = prm; A.counts = cnt; A.esA = esA; A.edA = edA;
    k_prep<<<13006 + 313, TB, 0, stream>>>(A);
  }

  // ---- CSR ----
  k_hist<<<gbE, TB, 0, stream>>>(eic, cnt);
  k_scan<<<1, 1024, 0, stream>>>(cnt, rp, cursor, col);
  k_scatter<<<gbE, TB, 0, stream>>>(eic, cursor, col);

  const int RB = (NN + 127)/128;                  // 157 row-bands of 128
  const int R8 = ((RB + 7)/8)*8;                  // 160 (padded, guard in kernel)
  dim3 g12(1024/128, R8);
  dim3 g3 (512/128,  R8);

  // ---- layer 1 (K=128) ----
  k_gemm_mfma<<<g12, TB, 0, stream>>>(Xc, Wt1, xw, as1, ad1, esA, edA, 128, 1024, 256, 4);
  k_aggln<<<NN/4, TB, 0, stream>>>(rp, col, xw, esA, edA, b1, lg1, lb1, act, esB, edB, 4);

  // ---- layer 2 (K=1024) ----
  k_gemm_mfma<<<g12, TB, 0, stream>>>(act, Wt2, xw, as2, ad2, esB, edB, 1024, 1024, 256, 4);
  k_aggln<<<NN/4, TB, 0, stream>>>(rp, col, xw, esB, edB, b2, lg2, lb2, act, esC, edC, 1);

  // ---- layer 3 (K=1024, M=512) ----
  k_gemm_mfma<<<g3, TB, 0, stream>>>(act, Wt3, xw, as3, ad3, esC, edC, 1024, 512, 512, 1);
  k_agg3<<<NN/4, TB, 0, stream>>>(rp, col, xw, esC, edC, b3, out);
}

// Round 2
// 460.143 us; speedup vs baseline: 1.0354x; 1.0354x over previous
//
#include <hip/hip_runtime.h>
#include <hip/hip_bf16.h>

typedef __hip_bfloat16 bf16;
typedef __attribute__((ext_vector_type(8))) short short8;
typedef __attribute__((ext_vector_type(4))) float float4v;

#define NN 20000
#define EE 160000
#define ET (NN + EE)

__device__ __forceinline__ float bf2f(bf16 v){ return __bfloat162float(v); }
__device__ __forceinline__ float raw2f(unsigned short u){ return __uint_as_float(((unsigned)u) << 16); }
__device__ __forceinline__ unsigned short f2raw(float f){
  bf16 h = __float2bfloat16(f);
  return *(unsigned short*)&h;
}

// ---------------- inline dtype detection (per-wave ballot; all waves agree) ----------------
__device__ __forceinline__ int detect_f32(const void* raw, int nwords, int lane){
  unsigned v = ((const unsigned*)raw)[lane % nwords];
  int e8 = (v >> 7) & 0xFF;
  int looks = (e8 >= 100 && e8 <= 140) ? 1 : 0;
  unsigned long long mz = __ballot(v == 0u);
  unsigned long long ml = __ballot(looks);
  int nz = __popcll(mz);
  int nonz = 64 - nz;
  int nl = __popcll(ml);
  return (nonz > 0 && 2*nl >= nonz) ? 0 : 1;
}

__device__ __forceinline__ int detect_i64(const int* eiraw, int lane){
  int odd = eiraw[2*lane + 1];
  unsigned long long m2 = __ballot(odd != 0);
  return (m2 == 0ULL) ? 1 : 0;
}

// ---------------- fused preprocessing kernel ----------------
struct P13 { const void* src[13]; int off[13]; int n[13]; };
struct PrepArgs {
  const void* xraw; bf16* Xc;
  const void* w1raw; bf16* Wt1;
  const void* w2raw; bf16* Wt2;
  const void* w3raw; bf16* Wt3;
  const int* eiraw; int* eic;
  P13 p13; float* prm;
  int* counts;
  float* esA; float* edA;
};

__device__ __forceinline__ void do_transpose(float (*tile)[33], const void* raw,
    bf16* wt, int K, int M, int f, int bx, int by, int t){
  int kb = by*32, mb = bx*32;
  int tx = t & 31, ty = t >> 5;   // 32 x 8
  for (int r = 0; r < 4; r++){
    int k = kb + ty + r*8;
    int m = mb + tx;
    float v = f ? ((const float*)raw)[(size_t)k*M+m] : bf2f(((const bf16*)raw)[(size_t)k*M+m]);
    tile[ty + r*8][tx] = v;
  }
  __syncthreads();
  for (int r = 0; r < 4; r++){
    int m = mb + ty + r*8;
    int k = kb + tx;
    wt[(size_t)m*K + k] = __float2bfloat16(tile[tx][ty + r*8]);
  }
}

__global__ __launch_bounds__(256) void k_prep(PrepArgs A){
  __shared__ float tile[32][33];
  int b = blockIdx.x, t = threadIdx.x;
  int lane = t & 63;
  if (b < 10000){                                 // cvt X -> bf16
    int f = detect_f32(A.xraw, NN*128/2, lane);
    int i = b*256 + t;
    if (f) A.Xc[i] = __float2bfloat16(((const float*)A.xraw)[i]);
    else   A.Xc[i] = ((const bf16*)A.xraw)[i];
  } else if (b < 10128){                          // transpose W1 [128][1024] -> [1024][128]
    int f = detect_f32(A.w1raw, 128*1024/2, lane);
    int r = b - 10000;
    do_transpose(tile, A.w1raw, A.Wt1, 128, 1024, f, r & 31, r >> 5, t);
  } else if (b < 11152){                          // transpose W2 [1024][1024]
    int f = detect_f32(A.w2raw, 1024*1024/2, lane);
    int r = b - 10128;
    do_transpose(tile, A.w2raw, A.Wt2, 1024, 1024, f, r & 31, r >> 5, t);
  } else if (b < 11664){                          // transpose W3 [1024][512] -> [512][1024]
    int f = detect_f32(A.w3raw, 1024*512/2, lane);
    int r = b - 11152;
    do_transpose(tile, A.w3raw, A.Wt3, 1024, 512, f, r & 15, r >> 4, t);
  } else if (b < 12914){                          // cvte
    int f64 = detect_i64(A.eiraw, lane);
    int i = (b - 11664)*256 + t;
    if (i < 2*EE) A.eic[i] = f64 ? A.eiraw[2*i] : A.eiraw[i];
  } else if (b < 12927){                          // params -> fp32
    int pb = b - 12914;
    const void* s = A.p13.src[pb];
    int n = A.p13.n[pb];
    int f = detect_f32(s, n/2, lane);
    float* d = A.prm + A.p13.off[pb];
    for (int i = t; i < n; i += 256)
      d[i] = f ? ((const float*)s)[i] : bf2f(((const bf16*)s)[i]);
  } else if (b < 13006){                          // init_counts
    int i = (b - 12927)*256 + t;
    if (i < NN) A.counts[i] = 1;
  } else {                                        // zero esA/edA (NN*4 floats each)
    int i = (b - 13006)*256 + t;
    if (i < NN*4){ A.esA[i] = 0.f; A.edA[i] = 0.f; }
  }
}

// ---------------- CSR build ----------------
__global__ void k_hist(const int* __restrict__ ei, int* __restrict__ counts){
  int e = blockIdx.x*256 + threadIdx.x;
  if (e < EE){
    int d = ei[EE + e];
    if (d >= 0 && d < NN) atomicAdd(&counts[d], 1);
  }
}

// scan + self-loop insertion fused; counts/rp/cursor/col are DISTINCT buffers (no aliasing)
__global__ __launch_bounds__(1024) void k_scan(const int* __restrict__ counts, int* __restrict__ rp,
    int* __restrict__ cursor, int* __restrict__ col){
  __shared__ int wsum[16];
  __shared__ int sc;
  int t = threadIdx.x, lane = t & 63, wv = t >> 6;
  if (t == 0) sc = 0;
  __syncthreads();
  for (int base = 0; base < NN; base += 1024){
    int i = base + t;
    int v = (i < NN) ? counts[i] : 0;
    int x = v;
    #pragma unroll
    for (int o = 1; o < 64; o <<= 1){
      int y = __shfl_up(x, o, 64);
      if (lane >= o) x += y;
    }
    if (lane == 63) wsum[wv] = x;
    __syncthreads();
    if (wv == 0 && lane < 16){
      int w = wsum[lane];
      #pragma unroll
      for (int o = 1; o < 16; o <<= 1){
        int y = __shfl_up(w, o, 16);
        if ((lane & 15) >= o) w += y;
      }
      wsum[lane] = w;
    }
    __syncthreads();
    int carry = sc;
    int wpre = (wv > 0) ? wsum[wv-1] : 0;
    if (i < NN){
      int p = carry + wpre + x - v;   // exclusive
      rp[i] = p;
      col[p] = i;                     // self loop at segment head
      cursor[i] = p + 1;
    }
    __syncthreads();
    if (t == 1023) sc = carry + wsum[15];
    __syncthreads();
  }
  if (t == 0) rp[NN] = sc;
}

__global__ void k_scatter(const int* __restrict__ ei, int* __restrict__ cursor, int* __restrict__ col){
  int e = blockIdx.x*256 + threadIdx.x;
  if (e < EE){
    int s = ei[e], d = ei[EE + e];
    if (d >= 0 && d < NN){
      int pos = atomicAdd(&cursor[d], 1);
      col[pos] = s;
    }
  }
}

// ---------------- MFMA GEMM: 64x128 tile, BK=64, double-buffered LDS (T3 minimum 2-phase) ----
// Round-1 lesson: at this shape (K=1024, M=20000) block residency dominates; 128^2 (144 regs ->
// ~2 blocks/CU) lost to 64x128 (~3.3 blocks/CU). Fix the STRUCTURE instead of the tile: dbuf LDS,
// issue next-tile global_load_lds BEFORE computing current tile, ONE __syncthreads per K-step.
// The vmcnt(0) inside __syncthreads now lands after ~250cy of ds_read+MFMA -> L2-hot load latency
// (weight panel + A re-reads are L2-resident) is covered intra-block instead of relying on other
// blocks. Statically distinct Xs0/Xs1/Bs0/Bs1 + hand-unrolled 2-step body so alias analysis cannot
// force a serializing wait between stage and ds_read. LDS 48KB -> 3 blocks/CU cap ~= observed 3.3.
// Per-element K-accumulation order identical (kk ascending) -> bit-identical output.
__device__ __forceinline__ void stage_tiles(const bf16* __restrict__ X, const bf16* __restrict__ Wt,
    bf16* xs, bf16* bs, int r0, int c0, int K, int tid, int k0){
  #pragma unroll
  for (int i = 0; i < 2; i++){            // Xs: 512 chunks of 16B
    int ch = i*256 + tid;
    int row = ch >> 3, kl = ch & 7;
    int kg = kl ^ (row & 7);
    const bf16* gx = X + (size_t)(r0 + row)*K + k0 + kg*8;
    __builtin_amdgcn_global_load_lds(
      (const __attribute__((address_space(1))) unsigned int*)gx,
      (__attribute__((address_space(3))) unsigned int*)(xs + ch*8), 16, 0, 0);
  }
  #pragma unroll
  for (int i = 0; i < 4; i++){            // Bs: 1024 chunks of 16B
    int ch = i*256 + tid;
    int row = ch >> 3, kl = ch & 7;
    int kg = kl ^ (row & 7);
    const bf16* gb = Wt + (size_t)(c0 + row)*K + k0 + kg*8;
    __builtin_amdgcn_global_load_lds(
      (const __attribute__((address_space(1))) unsigned int*)gb,
      (__attribute__((address_space(3))) unsigned int*)(bs + ch*8), 16, 0, 0);
  }
}

__device__ __forceinline__ void compute_step(const bf16* xb, const bf16* bb,
    int wr, int wc, int quad, int l15, int sw, float4v (&acc)[2][4]){
  #pragma unroll
  for (int kk = 0; kk < 2; kk++){         // two 32-wide K slices, in order (bit-identical accum)
    int kp = quad + kk*4;
    short8 af[2], bfr[4];
    #pragma unroll
    for (int i = 0; i < 2; i++){
      int r = wr + i*16 + l15;
      af[i] = *(const short8*)(xb + ((size_t)r*8 + (kp ^ sw))*8);
    }
    #pragma unroll
    for (int j = 0; j < 4; j++){
      int r = wc + j*16 + l15;
      bfr[j] = *(const short8*)(bb + ((size_t)r*8 + (kp ^ sw))*8);
    }
    #pragma unroll
    for (int i = 0; i < 2; i++)
      #pragma unroll
      for (int j = 0; j < 4; j++)
        acc[i][j] = __builtin_amdgcn_mfma_f32_16x16x32_bf16(af[i], bfr[j], acc[i][j], 0, 0, 0);
  }
}

__global__ __launch_bounds__(256) void k_gemm_mfma(
    const bf16* __restrict__ X, const bf16* __restrict__ Wt, bf16* __restrict__ Y,
    const float* __restrict__ as_, const float* __restrict__ ad_,
    float* __restrict__ es, float* __restrict__ ed,
    int K, int M, int C, int H)
{
  __shared__ bf16 Xs0[64*64];   // 8 KB
  __shared__ bf16 Xs1[64*64];   // 8 KB
  __shared__ bf16 Bs0[128*64];  // 16 KB
  __shared__ bf16 Bs1[128*64];  // 16 KB
  int ncols = gridDim.x;
  int bid = blockIdx.y * ncols + blockIdx.x;
  int xcd  = bid & 7;
  int rest = bid >> 3;
  int colb = rest % ncols;
  int rowb = xcd + 8 * (rest / ncols);
  int r0 = rowb * 64;
  if (r0 >= NN) return;
  int c0 = colb * 128;

  int tid  = threadIdx.x;
  int wave = tid >> 6, lane = tid & 63;
  int quad = lane >> 4, l15 = lane & 15;
  int wr = (wave >> 1) * 32;     // 2 row-groups of 32
  int wc = (wave & 1) * 64;      // 2 col-groups of 64
  int sw = l15 & 7;

  float4v acc[2][4];
  #pragma unroll
  for (int i=0;i<2;i++)
    #pragma unroll
    for (int j=0;j<4;j++)
      acc[i][j] = (float4v){0.f,0.f,0.f,0.f};

  int nst = K >> 6;   // 2 (layer1) or 16 (layers 2,3) -- always even
  // prologue: stage buffer 0 with k0 = 0
  stage_tiles(X, Wt, Xs0, Bs0, r0, c0, K, tid, 0);
  __syncthreads();

  for (int t = 0; t < nst; t += 2){
    // even step: compute buf0, prefetch buf1 (for t+1)
    if (t + 1 < nst) stage_tiles(X, Wt, Xs1, Bs1, r0, c0, K, tid, (t+1) << 6);
    compute_step(Xs0, Bs0, wr, wc, quad, l15, sw, acc);
    __syncthreads();
    if (t + 1 >= nst) break;
    // odd step: compute buf1, prefetch buf0 (for t+2)
    if (t + 2 < nst) stage_tiles(X, Wt, Xs0, Bs0, r0, c0, K, tid, (t+2) << 6);
    compute_step(Xs1, Bs1, wr, wc, quad, l15, sw, acc);
    if (t + 2 < nst) __syncthreads();
  }

  int h = c0 / C;
  float asv[4], adv[4];
  #pragma unroll
  for (int j = 0; j < 4; j++){
    int colj = c0 + wc + j*16 + l15;
    asv[j] = as_[colj]; adv[j] = ad_[colj];
  }
  #pragma unroll
  for (int i = 0; i < 2; i++){
    int rbase = r0 + wr + i*16 + quad*4;
    #pragma unroll
    for (int rg = 0; rg < 4; rg++){
      int row = rbase + rg;
      bool ok = (row < NN);
      float pe = 0.f, pd = 0.f;
      #pragma unroll
      for (int j = 0; j < 4; j++){
        float v = acc[i][j][rg];
        int colj = c0 + wc + j*16 + l15;
        if (ok) Y[(size_t)row*M + colj] = __float2bfloat16(v);
        pe += v * asv[j];
        pd += v * adv[j];
      }
      #pragma unroll
      for (int o = 1; o < 16; o <<= 1){
        pe += __shfl_xor(pe, o, 64);
        pd += __shfl_xor(pd, o, 64);
      }
      if (ok && l15 == 0){
        atomicAdd(&es[row*H + h], pe);
        atomicAdd(&ed[row*H + h], pd);
      }
    }
  }
}

// ---------------- wave-per-node softmax+aggregate+bias+LN+ELU (layers 1,2; H=4) ----------------
__global__ __launch_bounds__(256) void k_aggln(const int* __restrict__ rp, const int* __restrict__ col,
    const bf16* __restrict__ xw, const float* __restrict__ es, const float* __restrict__ ed,
    const float* __restrict__ bias, const float* __restrict__ gam, const float* __restrict__ bet,
    bf16* __restrict__ act, float* __restrict__ esz, float* __restrict__ edz, int zn){
  int wv = threadIdx.x >> 6, lane = threadIdx.x & 63;
  int n = blockIdx.x*4 + wv;              // NN % 4 == 0
  int h = lane >> 4;
  int cb = lane * 16;
  int e0 = rp[n], e1 = rp[n+1], deg = e1 - e0;
  float4 ed4 = *(const float4*)&ed[n*4];
  const unsigned short* xwu = (const unsigned short*)xw;

  float acc[16];
  #pragma unroll
  for (int c=0;c<16;c++) acc[c]=0.f;

  if (deg <= 64){
    int src = 0;
    float l0=-1e30f, l1=-1e30f, l2=-1e30f, l3=-1e30f;
    if (lane < deg){
      src = col[e0 + lane];
      float4 e4 = *(const float4*)&es[src*4];
      float v;
      v = e4.x + ed4.x; l0 = v > 0.f ? v : 0.2f*v;
      v = e4.y + ed4.y; l1 = v > 0.f ? v : 0.2f*v;
      v = e4.z + ed4.z; l2 = v > 0.f ? v : 0.2f*v;
      v = e4.w + ed4.w; l3 = v > 0.f ? v : 0.2f*v;
    }
    float m0=l0, m1=l1, m2=l2, m3=l3;
    #pragma unroll
    for (int o=1;o<64;o<<=1){
      m0 = fmaxf(m0, __shfl_xor(m0,o,64));
      m1 = fmaxf(m1, __shfl_xor(m1,o,64));
      m2 = fmaxf(m2, __shfl_xor(m2,o,64));
      m3 = fmaxf(m3, __shfl_xor(m3,o,64));
    }
    float p0 = (lane<deg) ? __expf(l0-m0) : 0.f;
    float p1 = (lane<deg) ? __expf(l1-m1) : 0.f;
    float p2 = (lane<deg) ? __expf(l2-m2) : 0.f;
    float p3 = (lane<deg) ? __expf(l3-m3) : 0.f;
    float d0=p0, d1=p1, d2=p2, d3=p3;
    #pragma unroll
    for (int o=1;o<64;o<<=1){
      d0 += __shfl_xor(d0,o,64);
      d1 += __shfl_xor(d1,o,64);
      d2 += __shfl_xor(d2,o,64);
      d3 += __shfl_xor(d3,o,64);
    }
    float al0 = p0 * (1.f/(d0+1e-16f));
    float al1 = p1 * (1.f/(d1+1e-16f));
    float al2 = p2 * (1.f/(d2+1e-16f));
    float al3 = p3 * (1.f/(d3+1e-16f));

    int j = 0;
    for (; j + 2 <= deg; j += 2){
      int sA = __shfl(src, j, 64);
      int sB = __shfl(src, j+1, 64);
      float a0A = __shfl(al0, j, 64), a1A = __shfl(al1, j, 64);
      float a2A = __shfl(al2, j, 64), a3A = __shfl(al3, j, 64);
      float a0B = __shfl(al0, j+1, 64), a1B = __shfl(al1, j+1, 64);
      float a2B = __shfl(al2, j+1, 64), a3B = __shfl(al3, j+1, 64);
      float aA = (h==0) ? a0A : ((h==1) ? a1A : ((h==2) ? a2A : a3A));
      float aB = (h==0) ? a0B : ((h==1) ? a1B : ((h==2) ? a2B : a3B));
      const unsigned short* rA = xwu + (size_t)sA*1024 + cb;
      const unsigned short* rB = xwu + (size_t)sB*1024 + cb;
      ushort4 uA0 = *(const ushort4*)(rA);
      ushort4 uA1 = *(const ushort4*)(rA+4);
      ushort4 uA2 = *(const ushort4*)(rA+8);
      ushort4 uA3 = *(const ushort4*)(rA+12);
      ushort4 uB0 = *(const ushort4*)(rB);
      ushort4 uB1 = *(const ushort4*)(rB+4);
      ushort4 uB2 = *(const ushort4*)(rB+8);
      ushort4 uB3 = *(const ushort4*)(rB+12);
      acc[0] += aA*raw2f(uA0.x); acc[1] += aA*raw2f(uA0.y); acc[2] += aA*raw2f(uA0.z); acc[3] += aA*raw2f(uA0.w);
      acc[4] += aA*raw2f(uA1.x); acc[5] += aA*raw2f(uA1.y); acc[6] += aA*raw2f(uA1.z); acc[7] += aA*raw2f(uA1.w);
      acc[8] += aA*raw2f(uA2.x); acc[9] += aA*raw2f(uA2.y); acc[10]+= aA*raw2f(uA2.z); acc[11]+= aA*raw2f(uA2.w);
      acc[12]+= aA*raw2f(uA3.x); acc[13]+= aA*raw2f(uA3.y); acc[14]+= aA*raw2f(uA3.z); acc[15]+= aA*raw2f(uA3.w);
      acc[0] += aB*raw2f(uB0.x); acc[1] += aB*raw2f(uB0.y); acc[2] += aB*raw2f(uB0.z); acc[3] += aB*raw2f(uB0.w);
      acc[4] += aB*raw2f(uB1.x); acc[5] += aB*raw2f(uB1.y); acc[6] += aB*raw2f(uB1.z); acc[7] += aB*raw2f(uB1.w);
      acc[8] += aB*raw2f(uB2.x); acc[9] += aB*raw2f(uB2.y); acc[10]+= aB*raw2f(uB2.z); acc[11]+= aB*raw2f(uB2.w);
      acc[12]+= aB*raw2f(uB3.x); acc[13]+= aB*raw2f(uB3.y); acc[14]+= aB*raw2f(uB3.z); acc[15]+= aB*raw2f(uB3.w);
    }
    for (; j < deg; j++){
      int s = __shfl(src, j, 64);
      float a0j = __shfl(al0, j, 64);
      float a1j = __shfl(al1, j, 64);
      float a2j = __shfl(al2, j, 64);
      float a3j = __shfl(al3, j, 64);
      float aj = (h==0) ? a0j : ((h==1) ? a1j : ((h==2) ? a2j : a3j));
      const unsigned short* row = xwu + (size_t)s*1024 + cb;
      ushort4 u0 = *(const ushort4*)(row);
      ushort4 u1 = *(const ushort4*)(row+4);
      ushort4 u2 = *(const ushort4*)(row+8);
      ushort4 u3 = *(const ushort4*)(row+12);
      acc[0] += aj*raw2f(u0.x); acc[1] += aj*raw2f(u0.y); acc[2] += aj*raw2f(u0.z); acc[3] += aj*raw2f(u0.w);
      acc[4] += aj*raw2f(u1.x); acc[5] += aj*raw2f(u1.y); acc[6] += aj*raw2f(u1.z); acc[7] += aj*raw2f(u1.w);
      acc[8] += aj*raw2f(u2.x); acc[9] += aj*raw2f(u2.y); acc[10]+= aj*raw2f(u2.z); acc[11]+= aj*raw2f(u2.w);
      acc[12]+= aj*raw2f(u3.x); acc[13]+= aj*raw2f(u3.y); acc[14]+= aj*raw2f(u3.z); acc[15]+= aj*raw2f(u3.w);
    }
  } else {
    float edh = (h==0) ? ed4.x : ((h==1) ? ed4.y : ((h==2) ? ed4.z : ed4.w));
    float m = -1e30f;
    for (int e=e0;e<e1;e++){
      float v = es[col[e]*4 + h] + edh;
      v = v > 0.f ? v : 0.2f*v;
      m = fmaxf(m, v);
    }
    float den = 0.f;
    for (int e=e0;e<e1;e++){
      float v = es[col[e]*4 + h] + edh;
      v = v > 0.f ? v : 0.2f*v;
      den += __expf(v - m);
    }
    float rd = 1.f/(den + 1e-16f);
    for (int e=e0;e<e1;e++){
      int s = col[e];
      float v = es[s*4 + h] + edh;
      v = v > 0.f ? v : 0.2f*v;
      float aj = __expf(v - m) * rd;
      const unsigned short* row = xwu + (size_t)s*1024 + cb;
      ushort4 u0 = *(const ushort4*)(row);
      ushort4 u1 = *(const ushort4*)(row+4);
      ushort4 u2 = *(const ushort4*)(row+8);
      ushort4 u3 = *(const ushort4*)(row+12);
      acc[0] += aj*raw2f(u0.x); acc[1] += aj*raw2f(u0.y); acc[2] += aj*raw2f(u0.z); acc[3] += aj*raw2f(u0.w);
      acc[4] += aj*raw2f(u1.x); acc[5] += aj*raw2f(u1.y); acc[6] += aj*raw2f(u1.z); acc[7] += aj*raw2f(u1.w);
      acc[8] += aj*raw2f(u2.x); acc[9] += aj*raw2f(u2.y); acc[10]+= aj*raw2f(u2.z); acc[11]+= aj*raw2f(u2.w);
      acc[12]+= aj*raw2f(u3.x); acc[13]+= aj*raw2f(u3.y); acc[14]+= aj*raw2f(u3.z); acc[15]+= aj*raw2f(u3.w);
    }
  }

  #pragma unroll
  for (int c=0;c<16;c++) acc[c] += bias[cb+c];
  float s1 = 0.f, s2 = 0.f;
  #pragma unroll
  for (int c=0;c<16;c++){ s1 += acc[c]; s2 += acc[c]*acc[c]; }
  #pragma unroll
  for (int o=1;o<64;o<<=1){
    s1 += __shfl_xor(s1,o,64);
    s2 += __shfl_xor(s2,o,64);
  }
  float mu  = s1 * (1.f/1024.f);
  float var = s2 * (1.f/1024.f) - mu*mu;
  float rstd = rsqrtf(fmaxf(var, 0.f) + 1e-5f);

  ushort4 o4[4];
  #pragma unroll
  for (int q=0;q<4;q++){
    float v0 = (acc[q*4+0]-mu)*rstd*gam[cb+q*4+0] + bet[cb+q*4+0];
    float v1 = (acc[q*4+1]-mu)*rstd*gam[cb+q*4+1] + bet[cb+q*4+1];
    float v2 = (acc[q*4+2]-mu)*rstd*gam[cb+q*4+2] + bet[cb+q*4+2];
    float v3 = (acc[q*4+3]-mu)*rstd*gam[cb+q*4+3] + bet[cb+q*4+3];
    v0 = v0 > 0.f ? v0 : (__expf(v0)-1.f);
    v1 = v1 > 0.f ? v1 : (__expf(v1)-1.f);
    v2 = v2 > 0.f ? v2 : (__expf(v2)-1.f);
    v3 = v3 > 0.f ? v3 : (__expf(v3)-1.f);
    o4[q].x = f2raw(v0); o4[q].y = f2raw(v1); o4[q].z = f2raw(v2); o4[q].w = f2raw(v3);
  }
  unsigned short* dst = (unsigned short*)act + (size_t)n*1024 + cb;
  *(ushort4*)(dst)    = o4[0];
  *(ushort4*)(dst+4)  = o4[1];
  *(ushort4*)(dst+8)  = o4[2];
  *(ushort4*)(dst+12) = o4[3];

  // zero next layer's logit slots for this node (exclusive ownership; read next dispatch)
  if (lane < zn){ esz[n*zn + lane] = 0.f; edz[n*zn + lane] = 0.f; }
}

// ---------------- wave-per-node layer-3: softmax + aggregate + bias -> fp32 out (H=1) ----------------
__global__ __launch_bounds__(256) void k_agg3(const int* __restrict__ rp, const int* __restrict__ col,
    const bf16* __restrict__ xw, const float* __restrict__ es, const float* __restrict__ ed,
    const float* __restrict__ bias, float* __restrict__ out){
  int wv = threadIdx.x >> 6, lane = threadIdx.x & 63;
  int n = blockIdx.x*4 + wv;
  int cb = lane * 8;
  int e0 = rp[n], e1 = rp[n+1], deg = e1 - e0;
  float edv = ed[n];
  const unsigned short* xwu = (const unsigned short*)xw;

  float acc[8];
  #pragma unroll
  for (int c=0;c<8;c++) acc[c]=0.f;

  if (deg <= 64){
    int src = 0;
    float l = -1e30f;
    if (lane < deg){
      src = col[e0 + lane];
      float v = es[src] + edv;
      l = v > 0.f ? v : 0.2f*v;
    }
    float m = l;
    #pragma unroll
    for (int o=1;o<64;o<<=1) m = fmaxf(m, __shfl_xor(m,o,64));
    float p = (lane<deg) ? __expf(l-m) : 0.f;
    float d = p;
    #pragma unroll
    for (int o=1;o<64;o<<=1) d += __shfl_xor(d,o,64);
    float al = p * (1.f/(d+1e-16f));

    int j = 0;
    for (; j + 2 <= deg; j += 2){
      int sA = __shfl(src, j, 64);
      int sB = __shfl(src, j+1, 64);
      float aA = __shfl(al, j, 64);
      float aB = __shfl(al, j+1, 64);
      const unsigned short* rA = xwu + (size_t)sA*512 + cb;
      const unsigned short* rB = xwu + (size_t)sB*512 + cb;
      ushort4 uA0 = *(const ushort4*)(rA);
      ushort4 uA1 = *(const ushort4*)(rA+4);
      ushort4 uB0 = *(const ushort4*)(rB);
      ushort4 uB1 = *(const ushort4*)(rB+4);
      acc[0] += aA*raw2f(uA0.x); acc[1] += aA*raw2f(uA0.y); acc[2] += aA*raw2f(uA0.z); acc[3] += aA*raw2f(uA0.w);
      acc[4] += aA*raw2f(uA1.x); acc[5] += aA*raw2f(uA1.y); acc[6] += aA*raw2f(uA1.z); acc[7] += aA*raw2f(uA1.w);
      acc[0] += aB*raw2f(uB0.x); acc[1] += aB*raw2f(uB0.y); acc[2] += aB*raw2f(uB0.z); acc[3] += aB*raw2f(uB0.w);
      acc[4] += aB*raw2f(uB1.x); acc[5] += aB*raw2f(uB1.y); acc[6] += aB*raw2f(uB1.z); acc[7] += aB*raw2f(uB1.w);
    }
    for (; j < deg; j++){
      int s = __shfl(src, j, 64);
      float aj = __shfl(al, j, 64);
      const unsigned short* row = xwu + (size_t)s*512 + cb;
      ushort4 u0 = *(const ushort4*)(row);
      ushort4 u1 = *(const ushort4*)(row+4);
      acc[0] += aj*raw2f(u0.x); acc[1] += aj*raw2f(u0.y); acc[2] += aj*raw2f(u0.z); acc[3] += aj*raw2f(u0.w);
      acc[4] += aj*raw2f(u1.x); acc[5] += aj*raw2f(u1.y); acc[6] += aj*raw2f(u1.z); acc[7] += aj*raw2f(u1.w);
    }
  } else {
    float m = -1e30f;
    for (int e=e0;e<e1;e++){
      float v = es[col[e]] + edv;
      v = v > 0.f ? v : 0.2f*v;
      m = fmaxf(m, v);
    }
    float den = 0.f;
    for (int e=e0;e<e1;e++){
      float v = es[col[e]] + edv;
      v = v > 0.f ? v : 0.2f*v;
      den += __expf(v - m);
    }
    float rd = 1.f/(den + 1e-16f);
    for (int e=e0;e<e1;e++){
      int s = col[e];
      float v = es[s] + edv;
      v = v > 0.f ? v : 0.2f*v;
      float aj = __expf(v - m) * rd;
      const unsigned short* row = xwu + (size_t)s*512 + cb;
      ushort4 u0 = *(const ushort4*)(row);
      ushort4 u1 = *(const ushort4*)(row+4);
      acc[0] += aj*raw2f(u0.x); acc[1] += aj*raw2f(u0.y); acc[2] += aj*raw2f(u0.z); acc[3] += aj*raw2f(u0.w);
      acc[4] += aj*raw2f(u1.x); acc[5] += aj*raw2f(u1.y); acc[6] += aj*raw2f(u1.z); acc[7] += aj*raw2f(u1.w);
    }
  }
  float* dst = out + (size_t)n*512 + cb;
  #pragma unroll
  for (int c=0;c<8;c++) dst[c] = acc[c] + bias[cb+c];
}

__global__ void k_wssmall(float* __restrict__ out, float code){
  if (threadIdx.x == 0) out[0] = code;
}

// ---------------- launch ----------------
extern "C" void kernel_launch(void* const* d_in, const int* in_sizes, int n_in,
                              void* d_out, int out_size, void* d_ws, size_t ws_size,
                              hipStream_t stream){
  float* out = (float*)d_out;
  char* ws = (char*)d_ws;

  static const int EXP_SZ[18] = {2560000, 320000, 131072, 1024,1024,1024,1024,1024,
                                 1048576, 1024,1024,1024,1024,1024,
                                 524288, 512,512,512};
  if (n_in != 18){ k_wssmall<<<1,64,0,stream>>>(out, 500.0f*301.0f); return; }
  for (int i = 0; i < 18; i++)
    if (in_sizes[i] != EXP_SZ[i]){ k_wssmall<<<1,64,0,stream>>>(out, 500.0f*302.0f); return; }
  if (out_size != NN*512){ k_wssmall<<<1,64,0,stream>>>(out, 500.0f*303.0f); return; }
  const size_t NEED = 93215360;
  if (ws_size < NEED){ k_wssmall<<<1,64,0,stream>>>(out, 500.0f*304.0f); return; }

  // ---- workspace layout ----
  bf16* xw    = (bf16*) (ws);                    // 40,960,000 (first 80KB doubles as CSR 'counts')
  int*  cnt   = (int*)  (ws);                    // aliases xw: counts, live prep->scan
  bf16* act   = (bf16*) (ws + 40960000);         // -> 81,920,000 (first 80KB doubles as CSR 'cursor')
  int*  cursor= (int*)  (ws + 40960000);         // aliases act: live scan->scatter
  bf16* Xc    = (bf16*) (ws + 81920000);         // -> 87,040,000 (dead after gemm1)
  float* esC  = (float*)(ws + 81920000);         // aliases Xc: 80,000 B (layer-3 logits, H=1)
  float* edC  = (float*)(ws + 82000000);         // aliases Xc: 80,000 B
  bf16* Wt1   = (bf16*) (ws + 87040000);         // -> 87,302,144
  bf16* Wt2   = (bf16*) (ws + 87302144);         // -> 89,399,296
  bf16* Wt3   = (bf16*) (ws + 89399296);         // -> 90,447,872
  float* prm  = (float*)(ws + 90447872);         // -> 90,494,976
  int*  eic   = (int*)  (ws + 90495232);         // -> 91,775,232 (dead after scatter)
  float* esB  = (float*)(ws + 90495232);         // aliases eic: 320,000 B (layer-2 logits)
  float* edB  = (float*)(ws + 90815232);         // aliases eic: 320,000 B
  float* esA  = (float*)(ws + 91775232);         // -> 92,095,232 (layer-1 logits)
  float* edA  = (float*)(ws + 92095232);         // -> 92,415,232
  int*  rp    = (int*)  (ws + 92415232);         // -> 92,495,360
  int*  col   = (int*)  (ws + 92495360);         // -> 93,215,360

  float *as1=prm+0, *ad1=prm+1024, *b1=prm+2048, *lg1=prm+3072, *lb1=prm+4096;
  float *as2=prm+5120, *ad2=prm+6144, *b2=prm+7168, *lg2=prm+8192, *lb2=prm+9216;
  float *as3=prm+10240, *ad3=prm+10752, *b3=prm+11264;

  const int TB = 256;
  int gbE = (EE + TB - 1)/TB;

  // ---- fused prep ----
  {
    PrepArgs A;
    A.xraw = d_in[0]; A.Xc = Xc;
    A.w1raw = d_in[2]; A.Wt1 = Wt1;
    A.w2raw = d_in[8]; A.Wt2 = Wt2;
    A.w3raw = d_in[14]; A.Wt3 = Wt3;
    A.eiraw = (const int*)d_in[1]; A.eic = eic;
    const int idx[13] = {3,4,5,6,7, 9,10,11,12,13, 15,16,17};
    const int off[13] = {0,1024,2048,3072,4096, 5120,6144,7168,8192,9216, 10240,10752,11264};
    const int nn [13] = {1024,1024,1024,1024,1024, 1024,1024,1024,1024,1024, 512,512,512};
    for (int i=0;i<13;i++){ A.p13.src[i]=d_in[idx[i]]; A.p13.off[i]=off[i]; A.p13.n[i]=nn[i]; }
    A.prm = prm; A.counts = cnt; A.esA = esA; A.edA = edA;
    k_prep<<<13006 + 313, TB, 0, stream>>>(A);
  }

  // ---- CSR ----
  k_hist<<<gbE, TB, 0, stream>>>(eic, cnt);
  k_scan<<<1, 1024, 0, stream>>>(cnt, rp, cursor, col);
  k_scatter<<<gbE, TB, 0, stream>>>(eic, cursor, col);

  const int RB = (NN + 63)/64;                    // 313 row-bands of 64
  const int R8 = ((RB + 7)/8)*8;                  // 320 (padded, guard in kernel)
  dim3 g12(1024/128, R8);
  dim3 g3 (512/128,  R8);

  // ---- layer 1 (K=128) ----
  k_gemm_mfma<<<g12, TB, 0, stream>>>(Xc, Wt1, xw, as1, ad1, esA, edA, 128, 1024, 256, 4);
  k_aggln<<<NN/4, TB, 0, stream>>>(rp, col, xw, esA, edA, b1, lg1, lb1, act, esB, edB, 4);

  // ---- layer 2 (K=1024) ----
  k_gemm_mfma<<<g12, TB, 0, stream>>>(act, Wt2, xw, as2, ad2, esB, edB, 1024, 1024, 256, 4);
  k_aggln<<<NN/4, TB, 0, stream>>>(rp, col, xw, esB, edB, b2, lg2, lb2, act, esC, edC, 1);

  // ---- layer 3 (K=1024, M=512) ----
  k_gemm_mfma<<<g3, TB, 0, stream>>>(act, Wt3, xw, as3, ad3, esC, edC, 1024, 512, 512, 1);
  k_agg3<<<NN/4, TB, 0, stream>>>(rp, col, xw, esC, edC, b3, out);
}

// Round 3
// 458.322 us; speedup vs baseline: 1.0395x; 1.0040x over previous
//
#include <hip/hip_runtime.h>
#include <hip/hip_bf16.h>

typedef __hip_bfloat16 bf16;
typedef __attribute__((ext_vector_type(8))) short short8;
typedef __attribute__((ext_vector_type(4))) float float4v;

#define NN 20000
#define EE 160000
#define ET (NN + EE)

__device__ __forceinline__ float bf2f(bf16 v){ return __bfloat162float(v); }
__device__ __forceinline__ float raw2f(unsigned short u){ return __uint_as_float(((unsigned)u) << 16); }
__device__ __forceinline__ unsigned short f2raw(float f){
  bf16 h = __float2bfloat16(f);
  return *(unsigned short*)&h;
}

// ---------------- inline dtype detection (per-wave ballot; all waves agree) ----------------
__device__ __forceinline__ int detect_f32(const void* raw, int nwords, int lane){
  unsigned v = ((const unsigned*)raw)[lane % nwords];
  int e8 = (v >> 7) & 0xFF;
  int looks = (e8 >= 100 && e8 <= 140) ? 1 : 0;
  unsigned long long mz = __ballot(v == 0u);
  unsigned long long ml = __ballot(looks);
  int nz = __popcll(mz);
  int nonz = 64 - nz;
  int nl = __popcll(ml);
  return (nonz > 0 && 2*nl >= nonz) ? 0 : 1;
}

__device__ __forceinline__ int detect_i64(const int* eiraw, int lane){
  int odd = eiraw[2*lane + 1];
  unsigned long long m2 = __ballot(odd != 0);
  return (m2 == 0ULL) ? 1 : 0;
}

// ---------------- fused preprocessing kernel ----------------
struct P13 { const void* src[13]; int off[13]; int n[13]; };
struct PrepArgs {
  const void* xraw; bf16* Xc;
  const void* w1raw; bf16* Wt1;
  const void* w2raw; bf16* Wt2;
  const void* w3raw; bf16* Wt3;
  const int* eiraw; int* eic;
  P13 p13; float* prm;
  int* counts;
  float* esA; float* edA;
};

__device__ __forceinline__ void do_transpose(float (*tile)[33], const void* raw,
    bf16* wt, int K, int M, int f, int bx, int by, int t){
  int kb = by*32, mb = bx*32;
  int tx = t & 31, ty = t >> 5;   // 32 x 8
  for (int r = 0; r < 4; r++){
    int k = kb + ty + r*8;
    int m = mb + tx;
    float v = f ? ((const float*)raw)[(size_t)k*M+m] : bf2f(((const bf16*)raw)[(size_t)k*M+m]);
    tile[ty + r*8][tx] = v;
  }
  __syncthreads();
  for (int r = 0; r < 4; r++){
    int m = mb + ty + r*8;
    int k = kb + tx;
    wt[(size_t)m*K + k] = __float2bfloat16(tile[tx][ty + r*8]);
  }
}

__global__ __launch_bounds__(256) void k_prep(PrepArgs A){
  __shared__ float tile[32][33];
  int b = blockIdx.x, t = threadIdx.x;
  int lane = t & 63;
  if (b < 10000){                                 // cvt X -> bf16
    int f = detect_f32(A.xraw, NN*128/2, lane);
    int i = b*256 + t;
    if (f) A.Xc[i] = __float2bfloat16(((const float*)A.xraw)[i]);
    else   A.Xc[i] = ((const bf16*)A.xraw)[i];
  } else if (b < 10128){                          // transpose W1 [128][1024] -> [1024][128]
    int f = detect_f32(A.w1raw, 128*1024/2, lane);
    int r = b - 10000;
    do_transpose(tile, A.w1raw, A.Wt1, 128, 1024, f, r & 31, r >> 5, t);
  } else if (b < 11152){                          // transpose W2 [1024][1024]
    int f = detect_f32(A.w2raw, 1024*1024/2, lane);
    int r = b - 10128;
    do_transpose(tile, A.w2raw, A.Wt2, 1024, 1024, f, r & 31, r >> 5, t);
  } else if (b < 11664){                          // transpose W3 [1024][512] -> [512][1024]
    int f = detect_f32(A.w3raw, 1024*512/2, lane);
    int r = b - 11152;
    do_transpose(tile, A.w3raw, A.Wt3, 1024, 512, f, r & 15, r >> 4, t);
  } else if (b < 12914){                          // cvte
    int f64 = detect_i64(A.eiraw, lane);
    int i = (b - 11664)*256 + t;
    if (i < 2*EE) A.eic[i] = f64 ? A.eiraw[2*i] : A.eiraw[i];
  } else if (b < 12927){                          // params -> fp32
    int pb = b - 12914;
    const void* s = A.p13.src[pb];
    int n = A.p13.n[pb];
    int f = detect_f32(s, n/2, lane);
    float* d = A.prm + A.p13.off[pb];
    for (int i = t; i < n; i += 256)
      d[i] = f ? ((const float*)s)[i] : bf2f(((const bf16*)s)[i]);
  } else if (b < 13006){                          // init_counts
    int i = (b - 12927)*256 + t;
    if (i < NN) A.counts[i] = 1;
  } else {                                        // zero esA/edA (NN*4 floats each)
    int i = (b - 13006)*256 + t;
    if (i < NN*4){ A.esA[i] = 0.f; A.edA[i] = 0.f; }
  }
}

// ---------------- CSR build ----------------
__global__ void k_hist(const int* __restrict__ ei, int* __restrict__ counts){
  int e = blockIdx.x*256 + threadIdx.x;
  if (e < EE){
    int d = ei[EE + e];
    if (d >= 0 && d < NN) atomicAdd(&counts[d], 1);
  }
}

// scan + self-loop insertion fused; counts/rp/cursor/col are DISTINCT buffers (no aliasing)
__global__ __launch_bounds__(1024) void k_scan(const int* __restrict__ counts, int* __restrict__ rp,
    int* __restrict__ cursor, int* __restrict__ col){
  __shared__ int wsum[16];
  __shared__ int sc;
  int t = threadIdx.x, lane = t & 63, wv = t >> 6;
  if (t == 0) sc = 0;
  __syncthreads();
  for (int base = 0; base < NN; base += 1024){
    int i = base + t;
    int v = (i < NN) ? counts[i] : 0;
    int x = v;
    #pragma unroll
    for (int o = 1; o < 64; o <<= 1){
      int y = __shfl_up(x, o, 64);
      if (lane >= o) x += y;
    }
    if (lane == 63) wsum[wv] = x;
    __syncthreads();
    if (wv == 0 && lane < 16){
      int w = wsum[lane];
      #pragma unroll
      for (int o = 1; o < 16; o <<= 1){
        int y = __shfl_up(w, o, 16);
        if ((lane & 15) >= o) w += y;
      }
      wsum[lane] = w;
    }
    __syncthreads();
    int carry = sc;
    int wpre = (wv > 0) ? wsum[wv-1] : 0;
    if (i < NN){
      int p = carry + wpre + x - v;   // exclusive
      rp[i] = p;
      col[p] = i;                     // self loop at segment head
      cursor[i] = p + 1;
    }
    __syncthreads();
    if (t == 1023) sc = carry + wsum[15];
    __syncthreads();
  }
  if (t == 0) rp[NN] = sc;
}

__global__ void k_scatter(const int* __restrict__ ei, int* __restrict__ cursor, int* __restrict__ col){
  int e = blockIdx.x*256 + threadIdx.x;
  if (e < EE){
    int s = ei[e], d = ei[EE + e];
    if (d >= 0 && d < NN){
      int pos = atomicAdd(&cursor[d], 1);
      col[pos] = s;
    }
  }
}

// ---------------- MFMA GEMM: 64x128 tile, BK=64, dbuf + COUNTED vmcnt (T3+T4) --------------
// Round-2 post-mortem: __syncthreads drains vmcnt(0), killing the prefetch (T4 lesson: dbuf's
// gain IS the counted wait). Fix: raw s_barrier + hand-counted s_waitcnt vmcnt(N).
// Each stage_tiles issues exactly SIX global_load_lds per thread (2 Xs + 4 Bs) -- vmcnt math
// depends on this. Pipeline: prologue stages buf0+buf1 (12 in flight); per step wait vmcnt(6)
// (current buf retired, next buf's 6 stay in flight ACROSS the barrier), barrier, compute,
// barrier, stage current buf for k+2. Final step waits vmcnt(0). Counted waits drain oldest-
// first, so any compiler-hoisted scalar loads only make waits more conservative (safe).
// sched_barrier(0) pins code motion around the raw barriers (rule #18 analog).
// Accumulation order identical -> bit-identical output (absmax is the race canary).
__device__ __forceinline__ void stage_tiles(const bf16* __restrict__ X, const bf16* __restrict__ Wt,
    bf16* xs, bf16* bs, int r0, int c0, int K, int tid, int k0){
  #pragma unroll
  for (int i = 0; i < 2; i++){            // Xs: 512 chunks of 16B
    int ch = i*256 + tid;
    int row = ch >> 3, kl = ch & 7;
    int kg = kl ^ (row & 7);
    const bf16* gx = X + (size_t)(r0 + row)*K + k0 + kg*8;
    __builtin_amdgcn_global_load_lds(
      (const __attribute__((address_space(1))) unsigned int*)gx,
      (__attribute__((address_space(3))) unsigned int*)(xs + ch*8), 16, 0, 0);
  }
  #pragma unroll
  for (int i = 0; i < 4; i++){            // Bs: 1024 chunks of 16B
    int ch = i*256 + tid;
    int row = ch >> 3, kl = ch & 7;
    int kg = kl ^ (row & 7);
    const bf16* gb = Wt + (size_t)(c0 + row)*K + k0 + kg*8;
    __builtin_amdgcn_global_load_lds(
      (const __attribute__((address_space(1))) unsigned int*)gb,
      (__attribute__((address_space(3))) unsigned int*)(bs + ch*8), 16, 0, 0);
  }
}

__device__ __forceinline__ void compute_step(const bf16* xb, const bf16* bb,
    int wr, int wc, int quad, int l15, int sw, float4v (&acc)[2][4]){
  #pragma unroll
  for (int kk = 0; kk < 2; kk++){         // two 32-wide K slices, in order (bit-identical accum)
    int kp = quad + kk*4;
    short8 af[2], bfr[4];
    #pragma unroll
    for (int i = 0; i < 2; i++){
      int r = wr + i*16 + l15;
      af[i] = *(const short8*)(xb + ((size_t)r*8 + (kp ^ sw))*8);
    }
    #pragma unroll
    for (int j = 0; j < 4; j++){
      int r = wc + j*16 + l15;
      bfr[j] = *(const short8*)(bb + ((size_t)r*8 + (kp ^ sw))*8);
    }
    #pragma unroll
    for (int i = 0; i < 2; i++)
      #pragma unroll
      for (int j = 0; j < 4; j++)
        acc[i][j] = __builtin_amdgcn_mfma_f32_16x16x32_bf16(af[i], bfr[j], acc[i][j], 0, 0, 0);
  }
}

__global__ __launch_bounds__(256) void k_gemm_mfma(
    const bf16* __restrict__ X, const bf16* __restrict__ Wt, bf16* __restrict__ Y,
    const float* __restrict__ as_, const float* __restrict__ ad_,
    float* __restrict__ es, float* __restrict__ ed,
    int K, int M, int C, int H)
{
  __shared__ bf16 Xs0[64*64];   // 8 KB
  __shared__ bf16 Xs1[64*64];   // 8 KB
  __shared__ bf16 Bs0[128*64];  // 16 KB
  __shared__ bf16 Bs1[128*64];  // 16 KB
  int ncols = gridDim.x;
  int bid = blockIdx.y * ncols + blockIdx.x;
  int xcd  = bid & 7;
  int rest = bid >> 3;
  int colb = rest % ncols;
  int rowb = xcd + 8 * (rest / ncols);
  int r0 = rowb * 64;
  if (r0 >= NN) return;
  int c0 = colb * 128;

  int tid  = threadIdx.x;
  int wave = tid >> 6, lane = tid & 63;
  int quad = lane >> 4, l15 = lane & 15;
  int wr = (wave >> 1) * 32;     // 2 row-groups of 32
  int wc = (wave & 1) * 64;      // 2 col-groups of 64
  int sw = l15 & 7;

  float4v acc[2][4];
  #pragma unroll
  for (int i=0;i<2;i++)
    #pragma unroll
    for (int j=0;j<4;j++)
      acc[i][j] = (float4v){0.f,0.f,0.f,0.f};

  int nst = K >> 6;   // 2 (layer1) or 16 (layers 2,3) -- always even
  // prologue: both buffers in flight (12 loads/wave outstanding)
  stage_tiles(X, Wt, Xs0, Bs0, r0, c0, K, tid, 0);
  stage_tiles(X, Wt, Xs1, Bs1, r0, c0, K, tid, 64);

  for (int t = 0; t < nst; t += 2){
    bool last = (t + 2 >= nst);

    // ---- even step: buf0 ----
    asm volatile("s_waitcnt vmcnt(6)" ::: "memory");   // buf0's 6 retired; buf1's 6 in flight
    __builtin_amdgcn_sched_barrier(0);
    __builtin_amdgcn_s_barrier();                      // all waves' buf0 loads landed
    __builtin_amdgcn_sched_barrier(0);
    compute_step(Xs0, Bs0, wr, wc, quad, l15, sw, acc);
    __builtin_amdgcn_sched_barrier(0);
    if (!last){
      __builtin_amdgcn_s_barrier();                    // all waves done reading buf0
      __builtin_amdgcn_sched_barrier(0);
      stage_tiles(X, Wt, Xs0, Bs0, r0, c0, K, tid, (t+2) << 6);  // -> 12 in flight
      asm volatile("s_waitcnt vmcnt(6)" ::: "memory"); // buf1's 6 retired; new buf0 in flight
    } else {
      asm volatile("s_waitcnt vmcnt(0)" ::: "memory"); // drain buf1 (no more prefetch)
    }
    __builtin_amdgcn_sched_barrier(0);

    // ---- odd step: buf1 ----
    __builtin_amdgcn_s_barrier();                      // all waves' buf1 loads landed
    __builtin_amdgcn_sched_barrier(0);
    compute_step(Xs1, Bs1, wr, wc, quad, l15, sw, acc);
    __builtin_amdgcn_sched_barrier(0);
    if (!last){
      __builtin_amdgcn_s_barrier();                    // all waves done reading buf1
      __builtin_amdgcn_sched_barrier(0);
      stage_tiles(X, Wt, Xs1, Bs1, r0, c0, K, tid, (t+3) << 6);  // -> 12 in flight
    }
  }

  int h = c0 / C;
  float asv[4], adv[4];
  #pragma unroll
  for (int j = 0; j < 4; j++){
    int colj = c0 + wc + j*16 + l15;
    asv[j] = as_[colj]; adv[j] = ad_[colj];
  }
  #pragma unroll
  for (int i = 0; i < 2; i++){
    int rbase = r0 + wr + i*16 + quad*4;
    #pragma unroll
    for (int rg = 0; rg < 4; rg++){
      int row = rbase + rg;
      bool ok = (row < NN);
      float pe = 0.f, pd = 0.f;
      #pragma unroll
      for (int j = 0; j < 4; j++){
        float v = acc[i][j][rg];
        int colj = c0 + wc + j*16 + l15;
        if (ok) Y[(size_t)row*M + colj] = __float2bfloat16(v);
        pe += v * asv[j];
        pd += v * adv[j];
      }
      #pragma unroll
      for (int o = 1; o < 16; o <<= 1){
        pe += __shfl_xor(pe, o, 64);
        pd += __shfl_xor(pd, o, 64);
      }
      if (ok && l15 == 0){
        atomicAdd(&es[row*H + h], pe);
        atomicAdd(&ed[row*H + h], pd);
      }
    }
  }
}

// ---------------- wave-per-node softmax+aggregate+bias+LN+ELU (layers 1,2; H=4) ----------------
__global__ __launch_bounds__(256) void k_aggln(const int* __restrict__ rp, const int* __restrict__ col,
    const bf16* __restrict__ xw, const float* __restrict__ es, const float* __restrict__ ed,
    const float* __restrict__ bias, const float* __restrict__ gam, const float* __restrict__ bet,
    bf16* __restrict__ act, float* __restrict__ esz, float* __restrict__ edz, int zn){
  int wv = threadIdx.x >> 6, lane = threadIdx.x & 63;
  int n = blockIdx.x*4 + wv;              // NN % 4 == 0
  int h = lane >> 4;
  int cb = lane * 16;
  int e0 = rp[n], e1 = rp[n+1], deg = e1 - e0;
  float4 ed4 = *(const float4*)&ed[n*4];
  const unsigned short* xwu = (const unsigned short*)xw;

  float acc[16];
  #pragma unroll
  for (int c=0;c<16;c++) acc[c]=0.f;

  if (deg <= 64){
    int src = 0;
    float l0=-1e30f, l1=-1e30f, l2=-1e30f, l3=-1e30f;
    if (lane < deg){
      src = col[e0 + lane];
      float4 e4 = *(const float4*)&es[src*4];
      float v;
      v = e4.x + ed4.x; l0 = v > 0.f ? v : 0.2f*v;
      v = e4.y + ed4.y; l1 = v > 0.f ? v : 0.2f*v;
      v = e4.z + ed4.z; l2 = v > 0.f ? v : 0.2f*v;
      v = e4.w + ed4.w; l3 = v > 0.f ? v : 0.2f*v;
    }
    float m0=l0, m1=l1, m2=l2, m3=l3;
    #pragma unroll
    for (int o=1;o<64;o<<=1){
      m0 = fmaxf(m0, __shfl_xor(m0,o,64));
      m1 = fmaxf(m1, __shfl_xor(m1,o,64));
      m2 = fmaxf(m2, __shfl_xor(m2,o,64));
      m3 = fmaxf(m3, __shfl_xor(m3,o,64));
    }
    float p0 = (lane<deg) ? __expf(l0-m0) : 0.f;
    float p1 = (lane<deg) ? __expf(l1-m1) : 0.f;
    float p2 = (lane<deg) ? __expf(l2-m2) : 0.f;
    float p3 = (lane<deg) ? __expf(l3-m3) : 0.f;
    float d0=p0, d1=p1, d2=p2, d3=p3;
    #pragma unroll
    for (int o=1;o<64;o<<=1){
      d0 += __shfl_xor(d0,o,64);
      d1 += __shfl_xor(d1,o,64);
      d2 += __shfl_xor(d2,o,64);
      d3 += __shfl_xor(d3,o,64);
    }
    float al0 = p0 * (1.f/(d0+1e-16f));
    float al1 = p1 * (1.f/(d1+1e-16f));
    float al2 = p2 * (1.f/(d2+1e-16f));
    float al3 = p3 * (1.f/(d3+1e-16f));

    int j = 0;
    for (; j + 2 <= deg; j += 2){
      int sA = __shfl(src, j, 64);
      int sB = __shfl(src, j+1, 64);
      float a0A = __shfl(al0, j, 64), a1A = __shfl(al1, j, 64);
      float a2A = __shfl(al2, j, 64), a3A = __shfl(al3, j, 64);
      float a0B = __shfl(al0, j+1, 64), a1B = __shfl(al1, j+1, 64);
      float a2B = __shfl(al2, j+1, 64), a3B = __shfl(al3, j+1, 64);
      float aA = (h==0) ? a0A : ((h==1) ? a1A : ((h==2) ? a2A : a3A));
      float aB = (h==0) ? a0B : ((h==1) ? a1B : ((h==2) ? a2B : a3B));
      const unsigned short* rA = xwu + (size_t)sA*1024 + cb;
      const unsigned short* rB = xwu + (size_t)sB*1024 + cb;
      ushort4 uA0 = *(const ushort4*)(rA);
      ushort4 uA1 = *(const ushort4*)(rA+4);
      ushort4 uA2 = *(const ushort4*)(rA+8);
      ushort4 uA3 = *(const ushort4*)(rA+12);
      ushort4 uB0 = *(const ushort4*)(rB);
      ushort4 uB1 = *(const ushort4*)(rB+4);
      ushort4 uB2 = *(const ushort4*)(rB+8);
      ushort4 uB3 = *(const ushort4*)(rB+12);
      acc[0] += aA*raw2f(uA0.x); acc[1] += aA*raw2f(uA0.y); acc[2] += aA*raw2f(uA0.z); acc[3] += aA*raw2f(uA0.w);
      acc[4] += aA*raw2f(uA1.x); acc[5] += aA*raw2f(uA1.y); acc[6] += aA*raw2f(uA1.z); acc[7] += aA*raw2f(uA1.w);
      acc[8] += aA*raw2f(uA2.x); acc[9] += aA*raw2f(uA2.y); acc[10]+= aA*raw2f(uA2.z); acc[11]+= aA*raw2f(uA2.w);
      acc[12]+= aA*raw2f(uA3.x); acc[13]+= aA*raw2f(uA3.y); acc[14]+= aA*raw2f(uA3.z); acc[15]+= aA*raw2f(uA3.w);
      acc[0] += aB*raw2f(uB0.x); acc[1] += aB*raw2f(uB0.y); acc[2] += aB*raw2f(uB0.z); acc[3] += aB*raw2f(uB0.w);
      acc[4] += aB*raw2f(uB1.x); acc[5] += aB*raw2f(uB1.y); acc[6] += aB*raw2f(uB1.z); acc[7] += aB*raw2f(uB1.w);
      acc[8] += aB*raw2f(uB2.x); acc[9] += aB*raw2f(uB2.y); acc[10]+= aB*raw2f(uB2.z); acc[11]+= aB*raw2f(uB2.w);
      acc[12]+= aB*raw2f(uB3.x); acc[13]+= aB*raw2f(uB3.y); acc[14]+= aB*raw2f(uB3.z); acc[15]+= aB*raw2f(uB3.w);
    }
    for (; j < deg; j++){
      int s = __shfl(src, j, 64);
      float a0j = __shfl(al0, j, 64);
      float a1j = __shfl(al1, j, 64);
      float a2j = __shfl(al2, j, 64);
      float a3j = __shfl(al3, j, 64);
      float aj = (h==0) ? a0j : ((h==1) ? a1j : ((h==2) ? a2j : a3j));
      const unsigned short* row = xwu + (size_t)s*1024 + cb;
      ushort4 u0 = *(const ushort4*)(row);
      ushort4 u1 = *(const ushort4*)(row+4);
      ushort4 u2 = *(const ushort4*)(row+8);
      ushort4 u3 = *(const ushort4*)(row+12);
      acc[0] += aj*raw2f(u0.x); acc[1] += aj*raw2f(u0.y); acc[2] += aj*raw2f(u0.z); acc[3] += aj*raw2f(u0.w);
      acc[4] += aj*raw2f(u1.x); acc[5] += aj*raw2f(u1.y); acc[6] += aj*raw2f(u1.z); acc[7] += aj*raw2f(u1.w);
      acc[8] += aj*raw2f(u2.x); acc[9] += aj*raw2f(u2.y); acc[10]+= aj*raw2f(u2.z); acc[11]+= aj*raw2f(u2.w);
      acc[12]+= aj*raw2f(u3.x); acc[13]+= aj*raw2f(u3.y); acc[14]+= aj*raw2f(u3.z); acc[15]+= aj*raw2f(u3.w);
    }
  } else {
    float edh = (h==0) ? ed4.x : ((h==1) ? ed4.y : ((h==2) ? ed4.z : ed4.w));
    float m = -1e30f;
    for (int e=e0;e<e1;e++){
      float v = es[col[e]*4 + h] + edh;
      v = v > 0.f ? v : 0.2f*v;
      m = fmaxf(m, v);
    }
    float den = 0.f;
    for (int e=e0;e<e1;e++){
      float v = es[col[e]*4 + h] + edh;
      v = v > 0.f ? v : 0.2f*v;
      den += __expf(v - m);
    }
    float rd = 1.f/(den + 1e-16f);
    for (int e=e0;e<e1;e++){
      int s = col[e];
      float v = es[s*4 + h] + edh;
      v = v > 0.f ? v : 0.2f*v;
      float aj = __expf(v - m) * rd;
      const unsigned short* row = xwu + (size_t)s*1024 + cb;
      ushort4 u0 = *(const ushort4*)(row);
      ushort4 u1 = *(const ushort4*)(row+4);
      ushort4 u2 = *(const ushort4*)(row+8);
      ushort4 u3 = *(const ushort4*)(row+12);
      acc[0] += aj*raw2f(u0.x); acc[1] += aj*raw2f(u0.y); acc[2] += aj*raw2f(u0.z); acc[3] += aj*raw2f(u0.w);
      acc[4] += aj*raw2f(u1.x); acc[5] += aj*raw2f(u1.y); acc[6] += aj*raw2f(u1.z); acc[7] += aj*raw2f(u1.w);
      acc[8] += aj*raw2f(u2.x); acc[9] += aj*raw2f(u2.y); acc[10]+= aj*raw2f(u2.z); acc[11]+= aj*raw2f(u2.w);
      acc[12]+= aj*raw2f(u3.x); acc[13]+= aj*raw2f(u3.y); acc[14]+= aj*raw2f(u3.z); acc[15]+= aj*raw2f(u3.w);
    }
  }

  #pragma unroll
  for (int c=0;c<16;c++) acc[c] += bias[cb+c];
  float s1 = 0.f, s2 = 0.f;
  #pragma unroll
  for (int c=0;c<16;c++){ s1 += acc[c]; s2 += acc[c]*acc[c]; }
  #pragma unroll
  for (int o=1;o<64;o<<=1){
    s1 += __shfl_xor(s1,o,64);
    s2 += __shfl_xor(s2,o,64);
  }
  float mu  = s1 * (1.f/1024.f);
  float var = s2 * (1.f/1024.f) - mu*mu;
  float rstd = rsqrtf(fmaxf(var, 0.f) + 1e-5f);

  ushort4 o4[4];
  #pragma unroll
  for (int q=0;q<4;q++){
    float v0 = (acc[q*4+0]-mu)*rstd*gam[cb+q*4+0] + bet[cb+q*4+0];
    float v1 = (acc[q*4+1]-mu)*rstd*gam[cb+q*4+1] + bet[cb+q*4+1];
    float v2 = (acc[q*4+2]-mu)*rstd*gam[cb+q*4+2] + bet[cb+q*4+2];
    float v3 = (acc[q*4+3]-mu)*rstd*gam[cb+q*4+3] + bet[cb+q*4+3];
    v0 = v0 > 0.f ? v0 : (__expf(v0)-1.f);
    v1 = v1 > 0.f ? v1 : (__expf(v1)-1.f);
    v2 = v2 > 0.f ? v2 : (__expf(v2)-1.f);
    v3 = v3 > 0.f ? v3 : (__expf(v3)-1.f);
    o4[q].x = f2raw(v0); o4[q].y = f2raw(v1); o4[q].z = f2raw(v2); o4[q].w = f2raw(v3);
  }
  unsigned short* dst = (unsigned short*)act + (size_t)n*1024 + cb;
  *(ushort4*)(dst)    = o4[0];
  *(ushort4*)(dst+4)  = o4[1];
  *(ushort4*)(dst+8)  = o4[2];
  *(ushort4*)(dst+12) = o4[3];

  // zero next layer's logit slots for this node (exclusive ownership; read next dispatch)
  if (lane < zn){ esz[n*zn + lane] = 0.f; edz[n*zn + lane] = 0.f; }
}

// ---------------- wave-per-node layer-3: softmax + aggregate + bias -> fp32 out (H=1) ----------------
__global__ __launch_bounds__(256) void k_agg3(const int* __restrict__ rp, const int* __restrict__ col,
    const bf16* __restrict__ xw, const float* __restrict__ es, const float* __restrict__ ed,
    const float* __restrict__ bias, float* __restrict__ out){
  int wv = threadIdx.x >> 6, lane = threadIdx.x & 63;
  int n = blockIdx.x*4 + wv;
  int cb = lane * 8;
  int e0 = rp[n], e1 = rp[n+1], deg = e1 - e0;
  float edv = ed[n];
  const unsigned short* xwu = (const unsigned short*)xw;

  float acc[8];
  #pragma unroll
  for (int c=0;c<8;c++) acc[c]=0.f;

  if (deg <= 64){
    int src = 0;
    float l = -1e30f;
    if (lane < deg){
      src = col[e0 + lane];
      float v = es[src] + edv;
      l = v > 0.f ? v : 0.2f*v;
    }
    float m = l;
    #pragma unroll
    for (int o=1;o<64;o<<=1) m = fmaxf(m, __shfl_xor(m,o,64));
    float p = (lane<deg) ? __expf(l-m) : 0.f;
    float d = p;
    #pragma unroll
    for (int o=1;o<64;o<<=1) d += __shfl_xor(d,o,64);
    float al = p * (1.f/(d+1e-16f));

    int j = 0;
    for (; j + 2 <= deg; j += 2){
      int sA = __shfl(src, j, 64);
      int sB = __shfl(src, j+1, 64);
      float aA = __shfl(al, j, 64);
      float aB = __shfl(al, j+1, 64);
      const unsigned short* rA = xwu + (size_t)sA*512 + cb;
      const unsigned short* rB = xwu + (size_t)sB*512 + cb;
      ushort4 uA0 = *(const ushort4*)(rA);
      ushort4 uA1 = *(const ushort4*)(rA+4);
      ushort4 uB0 = *(const ushort4*)(rB);
      ushort4 uB1 = *(const ushort4*)(rB+4);
      acc[0] += aA*raw2f(uA0.x); acc[1] += aA*raw2f(uA0.y); acc[2] += aA*raw2f(uA0.z); acc[3] += aA*raw2f(uA0.w);
      acc[4] += aA*raw2f(uA1.x); acc[5] += aA*raw2f(uA1.y); acc[6] += aA*raw2f(uA1.z); acc[7] += aA*raw2f(uA1.w);
      acc[0] += aB*raw2f(uB0.x); acc[1] += aB*raw2f(uB0.y); acc[2] += aB*raw2f(uB0.z); acc[3] += aB*raw2f(uB0.w);
      acc[4] += aB*raw2f(uB1.x); acc[5] += aB*raw2f(uB1.y); acc[6] += aB*raw2f(uB1.z); acc[7] += aB*raw2f(uB1.w);
    }
    for (; j < deg; j++){
      int s = __shfl(src, j, 64);
      float aj = __shfl(al, j, 64);
      const unsigned short* row = xwu + (size_t)s*512 + cb;
      ushort4 u0 = *(const ushort4*)(row);
      ushort4 u1 = *(const ushort4*)(row+4);
      acc[0] += aj*raw2f(u0.x); acc[1] += aj*raw2f(u0.y); acc[2] += aj*raw2f(u0.z); acc[3] += aj*raw2f(u0.w);
      acc[4] += aj*raw2f(u1.x); acc[5] += aj*raw2f(u1.y); acc[6] += aj*raw2f(u1.z); acc[7] += aj*raw2f(u1.w);
    }
  } else {
    float m = -1e30f;
    for (int e=e0;e<e1;e++){
      float v = es[col[e]] + edv;
      v = v > 0.f ? v : 0.2f*v;
      m = fmaxf(m, v);
    }
    float den = 0.f;
    for (int e=e0;e<e1;e++){
      float v = es[col[e]] + edv;
      v = v > 0.f ? v : 0.2f*v;
      den += __expf(v - m);
    }
    float rd = 1.f/(den + 1e-16f);
    for (int e=e0;e<e1;e++){
      int s = col[e];
      float v = es[s] + edv;
      v = v > 0.f ? v : 0.2f*v;
      float aj = __expf(v - m) * rd;
      const unsigned short* row = xwu + (size_t)s*512 + cb;
      ushort4 u0 = *(const ushort4*)(row);
      ushort4 u1 = *(const ushort4*)(row+4);
      acc[0] += aj*raw2f(u0.x); acc[1] += aj*raw2f(u0.y); acc[2] += aj*raw2f(u0.z); acc[3] += aj*raw2f(u0.w);
      acc[4] += aj*raw2f(u1.x); acc[5] += aj*raw2f(u1.y); acc[6] += aj*raw2f(u1.z); acc[7] += aj*raw2f(u1.w);
    }
  }
  float* dst = out + (size_t)n*512 + cb;
  #pragma unroll
  for (int c=0;c<8;c++) dst[c] = acc[c] + bias[cb+c];
}

__global__ void k_wssmall(float* __restrict__ out, float code){
  if (threadIdx.x == 0) out[0] = code;
}

// ---------------- launch ----------------
extern "C" void kernel_launch(void* const* d_in, const int* in_sizes, int n_in,
                              void* d_out, int out_size, void* d_ws, size_t ws_size,
                              hipStream_t stream){
  float* out = (float*)d_out;
  char* ws = (char*)d_ws;

  static const int EXP_SZ[18] = {2560000, 320000, 131072, 1024,1024,1024,1024,1024,
                                 1048576, 1024,1024,1024,1024,1024,
                                 524288, 512,512,512};
  if (n_in != 18){ k_wssmall<<<1,64,0,stream>>>(out, 500.0f*301.0f); return; }
  for (int i = 0; i < 18; i++)
    if (in_sizes[i] != EXP_SZ[i]){ k_wssmall<<<1,64,0,stream>>>(out, 500.0f*302.0f); return; }
  if (out_size != NN*512){ k_wssmall<<<1,64,0,stream>>>(out, 500.0f*303.0f); return; }
  const size_t NEED = 93215360;
  if (ws_size < NEED){ k_wssmall<<<1,64,0,stream>>>(out, 500.0f*304.0f); return; }

  // ---- workspace layout ----
  bf16* xw    = (bf16*) (ws);                    // 40,960,000 (first 80KB doubles as CSR 'counts')
  int*  cnt   = (int*)  (ws);                    // aliases xw: counts, live prep->scan
  bf16* act   = (bf16*) (ws + 40960000);         // -> 81,920,000 (first 80KB doubles as CSR 'cursor')
  int*  cursor= (int*)  (ws + 40960000);         // aliases act: live scan->scatter
  bf16* Xc    = (bf16*) (ws + 81920000);         // -> 87,040,000 (dead after gemm1)
  float* esC  = (float*)(ws + 81920000);         // aliases Xc: 80,000 B (layer-3 logits, H=1)
  float* edC  = (float*)(ws + 82000000);         // aliases Xc: 80,000 B
  bf16* Wt1   = (bf16*) (ws + 87040000);         // -> 87,302,144
  bf16* Wt2   = (bf16*) (ws + 87302144);         // -> 89,399,296
  bf16* Wt3   = (bf16*) (ws + 89399296);         // -> 90,447,872
  float* prm  = (float*)(ws + 90447872);         // -> 90,494,976
  int*  eic   = (int*)  (ws + 90495232);         // -> 91,775,232 (dead after scatter)
  float* esB  = (float*)(ws + 90495232);         // aliases eic: 320,000 B (layer-2 logits)
  float* edB  = (float*)(ws + 90815232);         // aliases eic: 320,000 B
  float* esA  = (float*)(ws + 91775232);         // -> 92,095,232 (layer-1 logits)
  float* edA  = (float*)(ws + 92095232);         // -> 92,415,232
  int*  rp    = (int*)  (ws + 92415232);         // -> 92,495,360
  int*  col   = (int*)  (ws + 92495360);         // -> 93,215,360

  float *as1=prm+0, *ad1=prm+1024, *b1=prm+2048, *lg1=prm+3072, *lb1=prm+4096;
  float *as2=prm+5120, *ad2=prm+6144, *b2=prm+7168, *lg2=prm+8192, *lb2=prm+9216;
  float *as3=prm+10240, *ad3=prm+10752, *b3=prm+11264;

  const int TB = 256;
  int gbE = (EE + TB - 1)/TB;

  // ---- fused prep ----
  {
    PrepArgs A;
    A.xraw = d_in[0]; A.Xc = Xc;
    A.w1raw = d_in[2]; A.Wt1 = Wt1;
    A.w2raw = d_in[8]; A.Wt2 = Wt2;
    A.w3raw = d_in[14]; A.Wt3 = Wt3;
    A.eiraw = (const int*)d_in[1]; A.eic = eic;
    const int idx[13] = {3,4,5,6,7, 9,10,11,12,13, 15,16,17};
    const int off[13] = {0,1024,2048,3072,4096, 5120,6144,7168,8192,9216, 10240,10752,11264};
    const int nn [13] = {1024,1024,1024,1024,1024, 1024,1024,1024,1024,1024, 512,512,512};
    for (int i=0;i<13;i++){ A.p13.src[i]=d_in[idx[i]]; A.p13.off[i]=off[i]; A.p13.n[i]=nn[i]; }
    A.prm = prm; A.counts = cnt; A.esA = esA; A.edA = edA;
    k_prep<<<13006 + 313, TB, 0, stream>>>(A);
  }

  // ---- CSR ----
  k_hist<<<gbE, TB, 0, stream>>>(eic, cnt);
  k_scan<<<1, 1024, 0, stream>>>(cnt, rp, cursor, col);
  k_scatter<<<gbE, TB, 0, stream>>>(eic, cursor, col);

  const int RB = (NN + 63)/64;                    // 313 row-bands of 64
  const int R8 = ((RB + 7)/8)*8;                  // 320 (padded, guard in kernel)
  dim3 g12(1024/128, R8);
  dim3 g3 (512/128,  R8);

  // ---- layer 1 (K=128) ----
  k_gemm_mfma<<<g12, TB, 0, stream>>>(Xc, Wt1, xw, as1, ad1, esA, edA, 128, 1024, 256, 4);
  k_aggln<<<NN/4, TB, 0, stream>>>(rp, col, xw, esA, edA, b1, lg1, lb1, act, esB, edB, 4);

  // ---- layer 2 (K=1024) ----
  k_gemm_mfma<<<g12, TB, 0, stream>>>(act, Wt2, xw, as2, ad2, esB, edB, 1024, 1024, 256, 4);
  k_aggln<<<NN/4, TB, 0, stream>>>(rp, col, xw, esB, edB, b2, lg2, lb2, act, esC, edC, 1);

  // ---- layer 3 (K=1024, M=512) ----
  k_gemm_mfma<<<g3, TB, 0, stream>>>(act, Wt3, xw, as3, ad3, esC, edC, 1024, 512, 512, 1);
  k_agg3<<<NN/4, TB, 0, stream>>>(rp, col, xw, esC, edC, b3, out);
}